// Round 15
// baseline (439.555 us; speedup 1.0000x reference)
//
#include <hip/hip_runtime.h>
#include <hip/hip_fp16.h>
#include <stdint.h>

#define AS1 __attribute__((address_space(1)))
#define AS3 __attribute__((address_space(3)))

typedef _Float16 f16x8 __attribute__((ext_vector_type(8)));
typedef float f32x4 __attribute__((ext_vector_type(4)));

static constexpr int NODES  = 50000;
static constexpr int EDGES  = 800000;
static constexpr int INDIM  = 512;
static constexpr int HIDDIM = 256;
static constexpr int NB_SCAN = (NODES + 255) / 256;   // 196
static constexpr int RED_BLOCKS = 64;
static constexpr int GEMM_MB256 = (NODES + 255) / 256; // 196 row-blocks (BM=256)
static constexpr int ZROW = 50000;                     // dedicated zero row
static constexpr int SLICE_ROWS = 50016;
static constexpr int SLICE_ELEMS = SLICE_ROWS * 32;    // f16 elems per 32-col slice
static constexpr int AGGS_BLOCKS = 100000;             // 8 slices x 12500 node-blocks

// ---------------- ws layout (bytes) ----------------
static constexpr size_t OFF_PART   = 0;          // f32 [8][12500][32] (12.8 MB)
static constexpr size_t OFF_PADCSR = 13000000;   // i32 [<=1.6M] padded adjacency (6.4MB)
static constexpr size_t OFF_POFF   = 20000000;   // i32 [50001]
static constexpr size_t OFF_DINV   = 20400000;   // f32 [50000]
static constexpr size_t OFF_BSUM   = 20700000;   // i32 [196]
static constexpr size_t OFF_BOFF   = 20704096;   // i32 [256]
static constexpr size_t OFF_P2     = 20710000;   // f32 [64][256]
static constexpr size_t OFF_HN     = 51200000;   // f16 slice-major [8][50016][32] (25.6MB)
static constexpr size_t OFF_H1P    = 76800000;   // f16 row-major [50000][256] (25.6MB)
static constexpr size_t OFF_W1T    = 102400000;  // f16 [256][512]
static constexpr size_t OFF_W2T    = 102662144;  // f16 [256][256]
static constexpr size_t OFF_DEG    = 102793216;  // i32 [50000]
static constexpr size_t OFF_FILL   = 102993216;  // i32 [50000]

__device__ __forceinline__ unsigned short f2h(float f) {
  __half h = __float2half_rn(f);
  return __builtin_bit_cast(unsigned short, h);
}
__device__ __forceinline__ void gload_lds16(const unsigned short* g, unsigned short* l) {
  __builtin_amdgcn_global_load_lds((const AS1 void*)g, (AS3 void*)l, 16, 0, 0);
}
__device__ __forceinline__ __half2 shfl_h2(__half2 v, int off) {
  unsigned u = __builtin_bit_cast(unsigned, v);
  u = __shfl_down(u, off);
  return __builtin_bit_cast(__half2, u);
}

// counted-wait primitives (T4)
#define WAITVM(N)  asm volatile("s_waitcnt vmcnt(" #N ")" ::: "memory")
#define WAITLGKM   asm volatile("s_waitcnt lgkmcnt(0)" ::: "memory")
#define HWBARRIER  { asm volatile("" ::: "memory"); __builtin_amdgcn_s_barrier(); \
                     asm volatile("" ::: "memory"); }

// ------- weight transpose->f16 + zero deg/fill + zero ZROW (fused) -------
__global__ __launch_bounds__(256) void transw_zero_kernel(const float* __restrict__ W1,
                                                          const float* __restrict__ W2,
                                                          unsigned short* __restrict__ W1T,
                                                          unsigned short* __restrict__ W2T,
                                                          int4* __restrict__ zreg,
                                                          unsigned short* __restrict__ hn16s) {
  int b = blockIdx.x, tid = threadIdx.x;
  if (b < 512) {                                    // W1T[n][k] = f16(W1[k][n])
    int t = b * 256 + tid; int n = t >> 9, k = t & 511;
    W1T[t] = f2h(W1[k * HIDDIM + n]);
  } else if (b < 768) {
    int u = (b - 512) * 256 + tid; int n = u >> 8, k = u & 255;
    W2T[u] = f2h(W2[k * HIDDIM + n]);
  } else if (b < 866) {                             // zero deg+fill (400000 B)
    int i = (b - 768) * 256 + tid;
    if (i < 25000) zreg[i] = int4{0, 0, 0, 0};
  } else {                                          // zero ZROW in all 8 slices
    int slice = tid >> 5, col = tid & 31;           // 256 = 8*32 exact
    hn16s[(size_t)slice * SLICE_ELEMS + (size_t)ZROW * 32 + col] = 0;
  }
}

// ---------------- degree histogram (inline int64-layout detect) ----------------
__global__ __launch_bounds__(256) void hist_kernel(const int* __restrict__ ei,
                                                   int* __restrict__ deg) {
  __shared__ int sflag;
  if (threadIdx.x < 64) {
    unsigned long long b = __ballot(ei[2 * threadIdx.x + 1] == 0);
    if (threadIdx.x == 0) sflag = (b == 0xFFFFFFFFFFFFFFFFull) ? 1 : 0;
  }
  __syncthreads();
  int f = sflag;
  int e = blockIdx.x * 256 + threadIdx.x;        // 3125*256 = 800000 exact
  int d = f ? ei[2 * (EDGES + e)] : ei[EDGES + e];
  atomicAdd(&deg[d], 1);
}

// -------- scan over PADDED degree (pdeg = (deg+16)&~15) + dinv --------
__global__ __launch_bounds__(256) void scan1_kernel(const int* __restrict__ deg,
                                                    int* __restrict__ poff,
                                                    int* __restrict__ bsum,
                                                    float* __restrict__ dinv) {
  __shared__ int s[256];
  int t = threadIdx.x, i = blockIdx.x * 256 + t;
  int d = (i < NODES) ? deg[i] : 0;
  int v = (i < NODES) ? ((d + 16) & ~15) : 0;        // self + pads to mult of 16
  if (i < NODES) dinv[i] = rsqrtf((float)(d + 1));   // +1 self-loop
  s[t] = v; __syncthreads();
  for (int off = 1; off < 256; off <<= 1) {
    int x = (t >= off) ? s[t - off] : 0;
    __syncthreads(); s[t] += x; __syncthreads();
  }
  if (i < NODES) poff[i] = s[t] - v;
  if (t == 255) bsum[blockIdx.x] = s[255];
}
__global__ __launch_bounds__(256) void scan2_kernel(const int* __restrict__ bsum,
                                                    int* __restrict__ boff,
                                                    int* __restrict__ poffN) {
  __shared__ int s[256];
  int t = threadIdx.x;
  int v = (t < NB_SCAN) ? bsum[t] : 0;
  s[t] = v; __syncthreads();
  for (int off = 1; off < 256; off <<= 1) {
    int x = (t >= off) ? s[t - off] : 0;
    __syncthreads(); s[t] += x; __syncthreads();
  }
  if (t < NB_SCAN) boff[t] = s[t] - v;
  if (t == 255) *poffN = s[255];
}
__global__ __launch_bounds__(256) void scan3_kernel(int* __restrict__ poff,
                                                    const int* __restrict__ boff) {
  int i = blockIdx.x * 256 + threadIdx.x;
  if (i < NODES) poff[i] += boff[blockIdx.x];
}

// -------- pad-fill: slot0 = self, tail slots = ZROW --------
__global__ __launch_bounds__(256) void padfill_kernel(const int* __restrict__ deg,
                                                      const int* __restrict__ poff,
                                                      int* __restrict__ padcsr) {
  int i = blockIdx.x * 256 + threadIdx.x;
  if (i < NODES) {
    int d = deg[i], b0 = poff[i], pd = (d + 16) & ~15;
    padcsr[b0] = i;
    for (int s = d + 1; s < pd; ++s) padcsr[b0 + s] = ZROW;
  }
}

// ---------------- CSR fill into padded slots (inline detect) ----------------
__global__ __launch_bounds__(256) void fill_kernel(const int* __restrict__ ei,
                                                   const int* __restrict__ poff,
                                                   int* __restrict__ fill,
                                                   int* __restrict__ padcsr) {
  __shared__ int sflag;
  if (threadIdx.x < 64) {
    unsigned long long b = __ballot(ei[2 * threadIdx.x + 1] == 0);
    if (threadIdx.x == 0) sflag = (b == 0xFFFFFFFFFFFFFFFFull) ? 1 : 0;
  }
  __syncthreads();
  int f = sflag;
  int e = blockIdx.x * 256 + threadIdx.x;
  int s, d;
  if (f) { s = ei[2 * e]; d = ei[2 * (EDGES + e)]; }
  else   { s = ei[e];     d = ei[EDGES + e]; }
  int p = atomicAdd(&fill[d], 1);
  padcsr[poff[d] + 1 + p] = s;
}

// ---------------- GEMM (R10 skeleton): BM=BN=256, BK=32, counted vmcnt, f16 MFMA ----
// Output f16 SLICE-MAJOR: slice = col>>5 = wc*2+(n>>1), cin = (n&1)*16+fr.
template<int K, bool AFP32>
__global__ __launch_bounds__(512, 2) void gemm_f16_kernel(const void* __restrict__ Av,
                                                          const unsigned short* __restrict__ BT,
                                                          const float* __restrict__ dinv,
                                                          unsigned short* __restrict__ Cs) {
  constexpr int NSTEP = K / 32;
  __shared__ unsigned short As[2][256 * 32];   // 16 KB per buf
  __shared__ unsigned short Bs[2][256 * 32];   // 16 KB per buf (total 64 KB)
  const int tid = threadIdx.x, wave = tid >> 6, lane = tid & 63;
  const int fr = lane & 15, q = lane >> 4;
  const int wr = wave >> 2, wc = wave & 3;     // 2m x 4n
  const int m0 = blockIdx.x * 256;

  const int lrow4 = lane >> 2;                 // 0..15: row within 16-row slab
  const int sgq   = (lane & 3) ^ (lrow4 & 3);  // pre-swizzled source 16B group
  const unsigned short* a16 = (const unsigned short*)Av;
  const float*          a32 = (const float*)Av;

  f32x4 acc[8][4] = {};
  float4 fa[4];                                // fp32 A staging regs

#define STAGE_B(buf, kb)                                                      \
  {                                                                           \
    _Pragma("unroll")                                                         \
    for (int c = 0; c < 2; ++c) {                                             \
      int rbase = wave * 32 + c * 16;                                         \
      int gr = rbase + lrow4;                                                 \
      gload_lds16(BT + (size_t)gr * K + (kb) + sgq * 8, &Bs[buf][rbase * 32]);\
    }                                                                         \
  }
#define STAGE_A16(buf, kb)                                                    \
  {                                                                           \
    _Pragma("unroll")                                                         \
    for (int c = 0; c < 2; ++c) {                                             \
      int rbase = wave * 32 + c * 16;                                         \
      int gr = m0 + rbase + lrow4; if (gr > NODES - 1) gr = NODES - 1;        \
      gload_lds16(a16 + (size_t)gr * K + (kb) + sgq * 8, &As[buf][rbase * 32]);\
    }                                                                         \
  }
#define LOAD_A32(kb)                                                          \
  {                                                                           \
    _Pragma("unroll")                                                         \
    for (int j = 0; j < 4; ++j) {                                             \
      int F = tid + j * 512;                                                  \
      int r0 = m0 + (F >> 3); if (r0 > NODES - 1) r0 = NODES - 1;             \
      fa[j] = *(const float4*)(a32 + (size_t)r0 * K + (kb) + (F & 7) * 4);    \
    }                                                                         \
  }
#define WRITE_A32(buf)                                                        \
  {                                                                           \
    _Pragma("unroll")                                                         \
    for (int j = 0; j < 4; ++j) {                                             \
      int F = tid + j * 512;                                                  \
      int row = F >> 3, g4 = F & 7;                                           \
      ushort4 o{f2h(fa[j].x), f2h(fa[j].y), f2h(fa[j].z), f2h(fa[j].w)};      \
      int col = (((g4 >> 1) ^ (row & 3)) * 8) + (g4 & 1) * 4;                 \
      *(ushort4*)&As[buf][row * 32 + col] = o;                                \
    }                                                                         \
  }

  // ---- prologue: tile 0 into buf 0 ----
  if constexpr (AFP32) { LOAD_A32(0); WRITE_A32(0); WAITLGKM; }
  else                 { STAGE_A16(0, 0); }
  STAGE_B(0, 0);

  for (int t = 0; t < NSTEP; ++t) {
    const int cur = t & 1, nxt = cur ^ 1;
    if (t + 1 < NSTEP) {
      const int kb1 = (t + 1) * 32;
      if constexpr (AFP32) { LOAD_A32(kb1); } else { STAGE_A16(nxt, kb1); }
      STAGE_B(nxt, kb1);
      if constexpr (AFP32) { WAITVM(6); } else { WAITVM(4); }
    } else {
      WAITVM(0);
    }
    HWBARRIER;

    f16x8 af[8], bq[4];
#pragma unroll
    for (int m = 0; m < 8; ++m) {
      int row = wr * 128 + m * 16 + fr;
      af[m] = *(const f16x8*)&As[cur][row * 32 + ((q ^ (row & 3)) * 8)];
    }
#pragma unroll
    for (int n = 0; n < 4; ++n) {
      int row = wc * 64 + n * 16 + fr;
      bq[n] = *(const f16x8*)&Bs[cur][row * 32 + ((q ^ (row & 3)) * 8)];
    }
#pragma unroll
    for (int m = 0; m < 8; ++m)
#pragma unroll
      for (int n = 0; n < 4; ++n)
        acc[m][n] = __builtin_amdgcn_mfma_f32_16x16x32_f16(af[m], bq[n], acc[m][n], 0, 0, 0);

    if (t + 1 < NSTEP) {
      if constexpr (AFP32) { WRITE_A32(nxt); WAITLGKM; }
    }
    HWBARRIER;
  }
#undef STAGE_B
#undef STAGE_A16
#undef LOAD_A32
#undef WRITE_A32

  // epilogue: C/D layout col=lane&15, row=q*4+reg; write f16 slice-major
  const int rq = q * 4;
#pragma unroll
  for (int m = 0; m < 8; ++m) {
    int rbase = m0 + wr * 128 + m * 16 + rq;
#pragma unroll
    for (int r = 0; r < 4; ++r) {
      int grow = rbase + r;
      if (grow < NODES) {
        float dv = dinv[grow];
#pragma unroll
        for (int n = 0; n < 4; ++n) {
          int slice = wc * 2 + (n >> 1);
          int cin = (n & 1) * 16 + fr;
          Cs[(size_t)slice * SLICE_ELEMS + (size_t)grow * 32 + cin] =
              f2h(acc[m][n][r] * dv);
        }
      }
    }
  }
}

// ------- slice-local aggregation: f16 payload, __hadd2, padded-16 walk -------
// Grid 100000 = 8 slices x 12500 node-blocks; blockIdx&7 -> slice (1 per XCD,
// 3.2MB L2-resident). Wave = 1 node; 4 lanes per item (16B = 8 f16 each);
// 16 items per iteration, branch-free (ZROW pads are zeros).
template<bool WRITE16>
__global__ __launch_bounds__(256) void aggs_kernel(const __half* __restrict__ hn16s,
                                                   const float* __restrict__ dinv,
                                                   const int* __restrict__ poff,
                                                   const int* __restrict__ padcsr,
                                                   const float* __restrict__ bias,
                                                   __half* __restrict__ h1p,
                                                   float* __restrict__ part) {
  __shared__ float sm[4][32];
  const int b = blockIdx.x;
  const int slice = b & 7, nb = b >> 3;
  const int wave = threadIdx.x >> 6, lane = threadIdx.x & 63;
  const int g = lane >> 2, c = lane & 3;
  const int node = nb * 4 + wave;
  const __half* base = hn16s + (size_t)slice * SLICE_ELEMS;
  const int p0 = poff[node];
  const int items = poff[node + 1] - p0;       // multiple of 16, >= 16
  const int* pc = padcsr + p0;
  __half2 z = __floats2half2_rn(0.f, 0.f);
  __half2 a0 = z, a1 = z, a2 = z, a3 = z;
  for (int it = 0; it < items; it += 16) {
    int row = pc[it + g];
    uint4 v = *(const uint4*)(base + (size_t)row * 32 + c * 8);
    a0 = __hadd2(a0, __builtin_bit_cast(__half2, v.x));
    a1 = __hadd2(a1, __builtin_bit_cast(__half2, v.y));
    a2 = __hadd2(a2, __builtin_bit_cast(__half2, v.z));
    a3 = __hadd2(a3, __builtin_bit_cast(__half2, v.w));
  }
#pragma unroll
  for (int off = 4; off < 64; off <<= 1) {
    a0 = __hadd2(a0, shfl_h2(a0, off));
    a1 = __hadd2(a1, shfl_h2(a1, off));
    a2 = __hadd2(a2, shfl_h2(a2, off));
    a3 = __hadd2(a3, shfl_h2(a3, off));
  }
  if (lane < 4) {                               // lane == c, g == 0
    float2 f0 = __half22float2(a0), f1 = __half22float2(a1);
    float2 f2 = __half22float2(a2), f3 = __half22float2(a3);
    float di = dinv[node];
    const float* bp = bias + slice * 32 + c * 8;
    float r0 = fmaxf(fmaf(di, f0.x, bp[0]), 0.f);
    float r1 = fmaxf(fmaf(di, f0.y, bp[1]), 0.f);
    float r2 = fmaxf(fmaf(di, f1.x, bp[2]), 0.f);
    float r3 = fmaxf(fmaf(di, f1.y, bp[3]), 0.f);
    float r4 = fmaxf(fmaf(di, f2.x, bp[4]), 0.f);
    float r5 = fmaxf(fmaf(di, f2.y, bp[5]), 0.f);
    float r6 = fmaxf(fmaf(di, f3.x, bp[6]), 0.f);
    float r7 = fmaxf(fmaf(di, f3.y, bp[7]), 0.f);
    if constexpr (WRITE16) {
      __half2 h0 = __floats2half2_rn(r0, r1), h1 = __floats2half2_rn(r2, r3);
      __half2 h2 = __floats2half2_rn(r4, r5), h3 = __floats2half2_rn(r6, r7);
      uint4 o{__builtin_bit_cast(unsigned, h0), __builtin_bit_cast(unsigned, h1),
              __builtin_bit_cast(unsigned, h2), __builtin_bit_cast(unsigned, h3)};
      *(uint4*)(h1p + (size_t)node * 256 + slice * 32 + c * 8) = o;
    } else {
      sm[wave][c * 8 + 0] = r0; sm[wave][c * 8 + 1] = r1;
      sm[wave][c * 8 + 2] = r2; sm[wave][c * 8 + 3] = r3;
      sm[wave][c * 8 + 4] = r4; sm[wave][c * 8 + 5] = r5;
      sm[wave][c * 8 + 6] = r6; sm[wave][c * 8 + 7] = r7;
    }
  }
  if constexpr (!WRITE16) {
    __syncthreads();
    int t = threadIdx.x;
    if (t < 32)
      part[((size_t)slice * 12500 + nb) * 32 + t] =
          sm[0][t] + sm[1][t] + sm[2][t] + sm[3][t];
  }
}

// ---------------- readout ----------------
__global__ __launch_bounds__(256) void reduce2_kernel(const float* __restrict__ part,
                                                      float* __restrict__ p2) {
  int t = threadIdx.x, b = blockIdx.x;              // 64 blocks
  int slice = t >> 5, c = t & 31;                   // global col = slice*32+c = t
  float s = 0.f;
  for (int nb = b; nb < 12500; nb += RED_BLOCKS)
    s += part[((size_t)slice * 12500 + nb) * 32 + c];
  p2[b * 256 + t] = s;
}
__global__ __launch_bounds__(256) void final_kernel(const float* __restrict__ p2,
                                                    const float* __restrict__ Wfc,
                                                    const float* __restrict__ bfc,
                                                    float* __restrict__ out) {
  __shared__ float red[256];
  int t = threadIdx.x;
  float s = 0.f;
  for (int b = 0; b < RED_BLOCKS; ++b) s += p2[b * 256 + t];
  float g = s * (1.0f / (float)NODES);
  red[t] = g * Wfc[t];
  __syncthreads();
  for (int off = 128; off > 0; off >>= 1) {
    if (t < off) red[t] += red[t + off];
    __syncthreads();
  }
  if (t == 0) {
    float z = red[0] + bfc[0];
    out[0] = 1.0f / (1.0f + expf(-z));
  }
}

// ---------------- launch ----------------
extern "C" void kernel_launch(void* const* d_in, const int* in_sizes, int n_in,
                              void* d_out, int out_size, void* d_ws, size_t ws_size,
                              hipStream_t stream) {
  (void)in_sizes; (void)n_in; (void)out_size; (void)ws_size;
  const float* x   = (const float*)d_in[0];
  const int*   ei  = (const int*)d_in[1];
  const float* W1  = (const float*)d_in[2];
  const float* b1  = (const float*)d_in[3];
  const float* W2  = (const float*)d_in[4];
  const float* b2  = (const float*)d_in[5];
  const float* Wfc = (const float*)d_in[6];
  const float* bfc = (const float*)d_in[7];
  float* out = (float*)d_out;
  char* ws = (char*)d_ws;

  unsigned short* hn16s = (unsigned short*)(ws + OFF_HN);
  __half*         hn16h = (__half*)(ws + OFF_HN);
  unsigned short* h1p16 = (unsigned short*)(ws + OFF_H1P);
  __half*         h1p_h = (__half*)(ws + OFF_H1P);
  unsigned short* w1t   = (unsigned short*)(ws + OFF_W1T);
  unsigned short* w2t   = (unsigned short*)(ws + OFF_W2T);
  int*   deg    = (int*)(ws + OFF_DEG);
  int*   fill   = (int*)(ws + OFF_FILL);
  int*   poff   = (int*)(ws + OFF_POFF);
  int*   padcsr = (int*)(ws + OFF_PADCSR);
  int*   bsum   = (int*)(ws + OFF_BSUM);
  int*   boff   = (int*)(ws + OFF_BOFF);
  float* part   = (float*)(ws + OFF_PART);
  float* p2     = (float*)(ws + OFF_P2);
  float* dinv   = (float*)(ws + OFF_DINV);

  transw_zero_kernel<<<867, 256, 0, stream>>>(W1, W2, w1t, w2t, (int4*)deg, hn16s);
  hist_kernel<<<EDGES / 256, 256, 0, stream>>>(ei, deg);
  scan1_kernel<<<NB_SCAN, 256, 0, stream>>>(deg, poff, bsum, dinv);
  scan2_kernel<<<1, 256, 0, stream>>>(bsum, boff, poff + NODES);
  scan3_kernel<<<NB_SCAN, 256, 0, stream>>>(poff, boff);
  padfill_kernel<<<NB_SCAN, 256, 0, stream>>>(deg, poff, padcsr);
  fill_kernel<<<EDGES / 256, 256, 0, stream>>>(ei, poff, fill, padcsr);

  gemm_f16_kernel<INDIM, true><<<GEMM_MB256, 512, 0, stream>>>(x, w1t, dinv, hn16s);
  aggs_kernel<true><<<AGGS_BLOCKS, 256, 0, stream>>>(hn16h, dinv, poff, padcsr, b1, h1p_h, nullptr);
  gemm_f16_kernel<HIDDIM, false><<<GEMM_MB256, 512, 0, stream>>>(h1p16, w2t, dinv, hn16s);
  aggs_kernel<false><<<AGGS_BLOCKS, 256, 0, stream>>>(hn16h, dinv, poff, padcsr, b2, nullptr, part);
  reduce2_kernel<<<RED_BLOCKS, 256, 0, stream>>>(part, p2);
  final_kernel<<<1, 256, 0, stream>>>(p2, Wfc, bfc, out);
}

// Round 16
// 275.942 us; speedup vs baseline: 1.5929x; 1.5929x over previous
//
#include <hip/hip_runtime.h>
#include <stdint.h>

#define AS1 __attribute__((address_space(1)))
#define AS3 __attribute__((address_space(3)))

typedef __bf16 bf16x8 __attribute__((ext_vector_type(8)));
typedef float  f32x4  __attribute__((ext_vector_type(4)));

static constexpr int NODES  = 50000;
static constexpr int EDGES  = 800000;
static constexpr int INDIM  = 512;
static constexpr int HIDDIM = 256;
static constexpr int NB_SCAN = (NODES + 255) / 256;   // 196
static constexpr int AGG_BLOCKS = NODES / 4;          // 12500 (exact)
static constexpr int RED_BLOCKS = 64;
static constexpr int GEMM_MB128 = (NODES + 127) / 128; // 391 row-blocks (BM=128)

// ---------------- ws layout (bytes) — R10's ----------------
static constexpr size_t OFF_PART = 0;            // f32  [12500][256]
static constexpr size_t OFF_HN   = 51200000;     // fp8  [50000][256] pre-scaled h (both layers)
static constexpr size_t OFF_H1P  = 76800000;     // bf16 [50000][256] relu(layer1) output
static constexpr size_t OFF_W1T  = 102400000;    // bf16 [256][512]
static constexpr size_t OFF_W2T  = 102662144;    // bf16 [256][256]
static constexpr size_t OFF_DEG  = 102793216;    // i32 [50000]
static constexpr size_t OFF_FILL = 102993216;    // i32 [50000]
static constexpr size_t OFF_ROWP = 103193216;    // i32 [50001]
static constexpr size_t OFF_CSR  = 103393280;    // i32 [800000]
static constexpr size_t OFF_BSUM = 106593280;    // i32 [196]
static constexpr size_t OFF_BOFF = 106594304;    // i32 [256]
static constexpr size_t OFF_P2   = 106595840;    // f32 [64][256]
static constexpr size_t OFF_DINV = 106661376;    // f32 [50000]

__device__ __forceinline__ unsigned short f2bf(float f) {
  unsigned u = __builtin_bit_cast(unsigned, f);
  unsigned r = (u + 0x7FFFu + ((u >> 16) & 1u)) >> 16;   // RNE
  return (unsigned short)r;
}
__device__ __forceinline__ unsigned char f2fp8(float f) {
  int p = __builtin_amdgcn_cvt_pk_fp8_f32(f, f, 0, false);   // OCP e4m3fn
  return (unsigned char)(p & 0xff);
}
__device__ __forceinline__ void acc_fp8(float4& a, unsigned u) {
  a.x += __builtin_amdgcn_cvt_f32_fp8(u, 0);
  a.y += __builtin_amdgcn_cvt_f32_fp8(u, 1);
  a.z += __builtin_amdgcn_cvt_f32_fp8(u, 2);
  a.w += __builtin_amdgcn_cvt_f32_fp8(u, 3);
}
__device__ __forceinline__ void gload_lds16(const unsigned short* g, unsigned short* l) {
  __builtin_amdgcn_global_load_lds((const AS1 void*)g, (AS3 void*)l, 16, 0, 0);
}

// counted-wait primitives (T4)
#define WAITVM(N)  asm volatile("s_waitcnt vmcnt(" #N ")" ::: "memory")
#define WAITLGKM   asm volatile("s_waitcnt lgkmcnt(0)" ::: "memory")
#define HWBARRIER  { asm volatile("" ::: "memory"); __builtin_amdgcn_s_barrier(); \
                     asm volatile("" ::: "memory"); }

// ---------------- weight transpose + bf16 + scratch zeroing (fused) ----------------
__global__ __launch_bounds__(256) void transw_zero_kernel(const float* __restrict__ W1,
                                                          const float* __restrict__ W2,
                                                          unsigned short* __restrict__ W1T,
                                                          unsigned short* __restrict__ W2T,
                                                          int4* __restrict__ zreg) {
  int b = blockIdx.x, tid = threadIdx.x;
  if (b < 512) {                                    // W1T[n][k] = W1[k][n]
    int t = b * 256 + tid; int n = t >> 9, k = t & 511;
    W1T[t] = f2bf(W1[k * HIDDIM + n]);
  } else if (b < 768) {
    int u = (b - 512) * 256 + tid; int n = u >> 8, k = u & 255;
    W2T[u] = f2bf(W2[k * HIDDIM + n]);
  } else {                                          // zero deg+fill (400000 B)
    int i = (b - 768) * 256 + tid;
    if (i < 25000) zreg[i] = int4{0, 0, 0, 0};
  }
}

// ---------------- degree histogram (inline int64-layout detect) ----------------
__global__ __launch_bounds__(256) void hist_kernel(const int* __restrict__ ei,
                                                   int* __restrict__ deg) {
  __shared__ int sflag;
  if (threadIdx.x < 64) {
    unsigned long long b = __ballot(ei[2 * threadIdx.x + 1] == 0);
    if (threadIdx.x == 0) sflag = (b == 0xFFFFFFFFFFFFFFFFull) ? 1 : 0;
  }
  __syncthreads();
  int f = sflag;
  int e = blockIdx.x * 256 + threadIdx.x;        // 3125*256 = 800000 exact
  int d = f ? ei[2 * (EDGES + e)] : ei[EDGES + e];
  atomicAdd(&deg[d], 1);
}

// ---------------- scan (3 kernels) + dinv ----------------
__global__ __launch_bounds__(256) void scan1_kernel(const int* __restrict__ deg,
                                                    int* __restrict__ rowptr,
                                                    int* __restrict__ bsum,
                                                    float* __restrict__ dinv) {
  __shared__ int s[256];
  int t = threadIdx.x, i = blockIdx.x * 256 + t;
  int v = (i < NODES) ? deg[i] : 0;
  if (i < NODES) dinv[i] = rsqrtf((float)(v + 1));   // +1 self-loop
  s[t] = v; __syncthreads();
  for (int off = 1; off < 256; off <<= 1) {
    int x = (t >= off) ? s[t - off] : 0;
    __syncthreads(); s[t] += x; __syncthreads();
  }
  if (i < NODES) rowptr[i] = s[t] - v;
  if (t == 255) bsum[blockIdx.x] = s[255];
}
__global__ __launch_bounds__(256) void scan2_kernel(const int* __restrict__ bsum,
                                                    int* __restrict__ boff,
                                                    int* __restrict__ rowptrN) {
  __shared__ int s[256];
  int t = threadIdx.x;
  int v = (t < NB_SCAN) ? bsum[t] : 0;
  s[t] = v; __syncthreads();
  for (int off = 1; off < 256; off <<= 1) {
    int x = (t >= off) ? s[t - off] : 0;
    __syncthreads(); s[t] += x; __syncthreads();
  }
  if (t < NB_SCAN) boff[t] = s[t] - v;
  if (t == 255) *rowptrN = s[255];
}
__global__ __launch_bounds__(256) void scan3_kernel(int* __restrict__ rowptr,
                                                    const int* __restrict__ boff) {
  int i = blockIdx.x * 256 + threadIdx.x;
  if (i < NODES) rowptr[i] += boff[blockIdx.x];
}

// ---------------- CSR fill (inline detect) ----------------
__global__ __launch_bounds__(256) void fill_kernel(const int* __restrict__ ei,
                                                   const int* __restrict__ rowptr,
                                                   int* __restrict__ fill,
                                                   int* __restrict__ csr) {
  __shared__ int sflag;
  if (threadIdx.x < 64) {
    unsigned long long b = __ballot(ei[2 * threadIdx.x + 1] == 0);
    if (threadIdx.x == 0) sflag = (b == 0xFFFFFFFFFFFFFFFFull) ? 1 : 0;
  }
  __syncthreads();
  int f = sflag;
  int e = blockIdx.x * 256 + threadIdx.x;
  int s, d;
  if (f) { s = ei[2 * e]; d = ei[2 * (EDGES + e)]; }
  else   { s = ei[e];     d = ei[EDGES + e]; }
  int p = atomicAdd(&fill[d], 1);
  csr[rowptr[d] + p] = s;
}

// ======================= DEEP-PIPELINE GEMMs (D=3) =======================
// BM=128 x BN=256, BK=32, 512 thr / 8 waves (2m x 4n, wave tile 64x64).
// Triple-buffered LDS (72KB): stage tile t+2 while computing tile t ->
// ~2 tiles (48KB/block) of loads permanently in flight. Counted vmcnt only.
// Little's law: 256 CU x 48KB = 12MB in flight >> 6.3MB needed for peak HBM.

// shared compute step (both gemms): 16 MFMA on buffer `cur`
#define G_COMPUTE(cur)                                                        \
  {                                                                           \
    bf16x8 af[4], bq[4];                                                      \
    _Pragma("unroll")                                                         \
    for (int m = 0; m < 4; ++m) {                                             \
      int row = wr * 64 + m * 16 + fr;                                        \
      af[m] = *(const bf16x8*)&As[(cur) * 4096 + row * 32 + ((q ^ (row & 3)) * 8)]; \
    }                                                                         \
    _Pragma("unroll")                                                         \
    for (int n = 0; n < 4; ++n) {                                             \
      int row = wc * 64 + n * 16 + fr;                                        \
      bq[n] = *(const bf16x8*)&Bs[(cur) * 8192 + row * 32 + ((q ^ (row & 3)) * 8)]; \
    }                                                                         \
    _Pragma("unroll")                                                         \
    for (int m = 0; m < 4; ++m)                                               \
      _Pragma("unroll")                                                       \
      for (int n = 0; n < 4; ++n)                                             \
        acc[m][n] = __builtin_amdgcn_mfma_f32_16x16x32_bf16(af[m], bq[n], acc[m][n], 0, 0, 0); \
  }

#define G_EPILOGUE                                                            \
  {                                                                           \
    const int rq = q * 4;                                                     \
    _Pragma("unroll")                                                         \
    for (int m = 0; m < 4; ++m) {                                             \
      int rbase = m0 + wr * 64 + m * 16 + rq;                                 \
      _Pragma("unroll")                                                       \
      for (int r = 0; r < 4; ++r) {                                           \
        int grow = rbase + r;                                                 \
        if (grow < NODES) {                                                   \
          float dv = dinv[grow];                                              \
          _Pragma("unroll")                                                   \
          for (int n = 0; n < 4; ++n) {                                       \
            int gcol = wc * 64 + n * 16 + fr;                                 \
            Cn8[(size_t)grow * 256 + gcol] = f2fp8(acc[m][n][r] * dv);        \
          }                                                                   \
        }                                                                     \
      }                                                                       \
    }                                                                         \
  }

// B stage: 256x32 bf16 = 16KB = 1024 16B-chunks, 2/thread (2 vm ops/wave)
#define G_STAGEB(buf, kb)                                                     \
  {                                                                           \
    _Pragma("unroll")                                                         \
    for (int j = 0; j < 2; ++j) {                                             \
      int F = tid + j * 512;                                                  \
      int row = F >> 2, g = F & 3;                                            \
      gload_lds16(BT + (size_t)row * K + (kb) + ((g ^ (row & 3)) * 8),        \
                  Bs + (buf) * 8192 + F * 8);                                 \
    }                                                                         \
  }

// ---------------- GEMM1: fp32 A, reg-staged (2-set ping-pong), D=3 ----------------
__global__ __launch_bounds__(512, 2) void gemm1_deep(const float* __restrict__ A,
                                                     const unsigned short* __restrict__ BT,
                                                     const float* __restrict__ dinv,
                                                     unsigned char* __restrict__ Cn8) {
  constexpr int K = INDIM, NSTEP = K / 32;          // 16
  __shared__ unsigned short As[3 * 128 * 32];       // 24 KB
  __shared__ unsigned short Bs[3 * 256 * 32];       // 48 KB (total 72)
  const int tid = threadIdx.x, wave = tid >> 6, lane = tid & 63;
  const int fr = lane & 15, q = lane >> 4;
  const int wr = wave >> 2, wc = wave & 3;          // 2m x 4n
  const int m0 = blockIdx.x * 128;

  f32x4 acc[4][4] = {};
  float4 fa0[2], fa1[2];                            // two A-tile reg sets

  // A fp32: 128x32 = 16KB; 2 float4/thread (2 vm ops/wave)
#define G1_LOADA(fa, kb)                                                      \
  {                                                                           \
    _Pragma("unroll")                                                         \
    for (int j = 0; j < 2; ++j) {                                             \
      int F = tid + j * 512;                                                  \
      int row = F >> 3;                                                       \
      int gr = m0 + row; if (gr > NODES - 1) gr = NODES - 1;                  \
      fa[j] = *(const float4*)(A + (size_t)gr * K + (kb) + (F & 7) * 4);      \
    }                                                                         \
  }
#define G1_WRITEA(buf, fa)                                                    \
  {                                                                           \
    _Pragma("unroll")                                                         \
    for (int j = 0; j < 2; ++j) {                                             \
      int F = tid + j * 512;                                                  \
      int row = F >> 3, g8 = F & 7;                                           \
      ushort4 o{f2bf(fa[j].x), f2bf(fa[j].y), f2bf(fa[j].z), f2bf(fa[j].w)};  \
      int col = (((g8 >> 1) ^ (row & 3)) * 8) + (g8 & 1) * 4;                 \
      *(ushort4*)&As[(buf) * 4096 + row * 32 + col] = o;                      \
    }                                                                         \
  }
  // body: faH holds A(t+1); faL receives A(t+2)
#define G1_BODY(t, faH, faL)                                                  \
  {                                                                           \
    if ((t) + 2 < NSTEP) {                                                    \
      G1_LOADA(faL, ((t) + 2) * 32);                                          \
      G_STAGEB(((t) + 2) % 3, ((t) + 2) * 32);                                \
      WAITVM(8);                                                              \
    } else if ((t) + 1 < NSTEP) { WAITVM(4); } else { WAITVM(0); }            \
    HWBARRIER;                                                                \
    G_COMPUTE((t) % 3);                                                       \
    if ((t) + 1 < NSTEP) { G1_WRITEA(((t) + 1) % 3, faH); WAITLGKM; }         \
    HWBARRIER;                                                                \
  }

  // prologue: tile0 A->LDS, tile0/1 B staged, tile1 A in regs
  G1_LOADA(fa0, 0);
  G_STAGEB(0, 0);
  G1_WRITEA(0, fa0);                                // compiler waits fa0 loads
  G1_LOADA(fa1, 32);
  G_STAGEB(1, 32);
  WAITLGKM;                                         // A0 ds_writes drained

  for (int tt = 0; tt < NSTEP; tt += 2) {           // NSTEP=16 even
    G1_BODY(tt,     fa1, fa0);
    G1_BODY(tt + 1, fa0, fa1);
  }
#undef G1_LOADA
#undef G1_WRITEA
#undef G1_BODY

  G_EPILOGUE;
}

// ---------------- GEMM2: bf16 A via gload_lds, D=3 ----------------
__global__ __launch_bounds__(512, 2) void gemm2_deep(const unsigned short* __restrict__ A16,
                                                     const unsigned short* __restrict__ BT,
                                                     const float* __restrict__ dinv,
                                                     unsigned char* __restrict__ Cn8) {
  constexpr int K = HIDDIM, NSTEP = K / 32;         // 8
  __shared__ unsigned short As[3 * 128 * 32];       // 24 KB
  __shared__ unsigned short Bs[3 * 256 * 32];       // 48 KB
  const int tid = threadIdx.x, wave = tid >> 6, lane = tid & 63;
  const int fr = lane & 15, q = lane >> 4;
  const int wr = wave >> 2, wc = wave & 3;
  const int m0 = blockIdx.x * 128;

  f32x4 acc[4][4] = {};

  // A bf16: 128x32 = 8KB = 512 chunks, 1/thread (1 vm op/wave)
#define G2_STAGEA(buf, kb)                                                    \
  {                                                                           \
    int row = tid >> 2, g = tid & 3;                                          \
    int gr = m0 + row; if (gr > NODES - 1) gr = NODES - 1;                    \
    gload_lds16(A16 + (size_t)gr * K + (kb) + ((g ^ (row & 3)) * 8),          \
                As + (buf) * 4096 + tid * 8);                                 \
  }

  G2_STAGEA(0, 0);
  G_STAGEB(0, 0);
  G2_STAGEA(1, 32);
  G_STAGEB(1, 32);

  for (int t = 0; t < NSTEP; ++t) {
    if (t + 2 < NSTEP) {
      G2_STAGEA((t + 2) % 3, (t + 2) * 32);
      G_STAGEB((t + 2) % 3, (t + 2) * 32);
      WAITVM(6);
    } else if (t + 1 < NSTEP) { WAITVM(3); } else { WAITVM(0); }
    HWBARRIER;
    G_COMPUTE(t % 3);
    HWBARRIER;
  }
#undef G2_STAGEA

  G_EPILOGUE;
}

// ---------------- gather core: fp8 rows, unroll-8 (R10 verbatim) ----------------
__device__ __forceinline__ float4 gather_node(const unsigned char* __restrict__ hn8,
                                              const int* __restrict__ rowptr,
                                              const int* __restrict__ csr,
                                              int node, int boff) {
  float4 A{0.f, 0.f, 0.f, 0.f}, B{0.f, 0.f, 0.f, 0.f};
  unsigned us = *(const unsigned*)(hn8 + (size_t)node * 256 + boff);   // self-loop
  acc_fp8(A, us);
  int e0 = rowptr[node], e1 = rowptr[node + 1];
  int e = e0;
  for (; e + 8 <= e1; e += 8) {
    unsigned u0 = *(const unsigned*)(hn8 + (size_t)csr[e + 0] * 256 + boff);
    unsigned u1 = *(const unsigned*)(hn8 + (size_t)csr[e + 1] * 256 + boff);
    unsigned u2 = *(const unsigned*)(hn8 + (size_t)csr[e + 2] * 256 + boff);
    unsigned u3 = *(const unsigned*)(hn8 + (size_t)csr[e + 3] * 256 + boff);
    unsigned u4 = *(const unsigned*)(hn8 + (size_t)csr[e + 4] * 256 + boff);
    unsigned u5 = *(const unsigned*)(hn8 + (size_t)csr[e + 5] * 256 + boff);
    unsigned u6 = *(const unsigned*)(hn8 + (size_t)csr[e + 6] * 256 + boff);
    unsigned u7 = *(const unsigned*)(hn8 + (size_t)csr[e + 7] * 256 + boff);
    acc_fp8(A, u0); acc_fp8(B, u1); acc_fp8(A, u2); acc_fp8(B, u3);
    acc_fp8(A, u4); acc_fp8(B, u5); acc_fp8(A, u6); acc_fp8(B, u7);
  }
  for (; e + 4 <= e1; e += 4) {
    unsigned u0 = *(const unsigned*)(hn8 + (size_t)csr[e + 0] * 256 + boff);
    unsigned u1 = *(const unsigned*)(hn8 + (size_t)csr[e + 1] * 256 + boff);
    unsigned u2 = *(const unsigned*)(hn8 + (size_t)csr[e + 2] * 256 + boff);
    unsigned u3 = *(const unsigned*)(hn8 + (size_t)csr[e + 3] * 256 + boff);
    acc_fp8(A, u0); acc_fp8(B, u1); acc_fp8(A, u2); acc_fp8(B, u3);
  }
  for (; e < e1; ++e) {
    unsigned u = *(const unsigned*)(hn8 + (size_t)csr[e] * 256 + boff);
    acc_fp8(A, u);
  }
  return float4{A.x + B.x, A.y + B.y, A.z + B.z, A.w + B.w};
}

// ---------------- aggregation (R10 verbatim): agg1 -> bf16 h1p ----------------
__global__ __launch_bounds__(256) void agg1_kernel(const unsigned char* __restrict__ hn8,
                                                   const float* __restrict__ dinv,
                                                   const int* __restrict__ rowptr,
                                                   const int* __restrict__ csr,
                                                   const float* __restrict__ bias,
                                                   unsigned short* __restrict__ outp) {
  int wave = threadIdx.x >> 6, lane = threadIdx.x & 63;
  int node = blockIdx.x * 4 + wave;
  int c0 = lane * 4;
  float4 a = gather_node(hn8, rowptr, csr, node, c0);
  float di = dinv[node];
  float4 b = *(const float4*)(bias + c0);
  ushort4 o{f2bf(fmaxf(fmaf(di, a.x, b.x), 0.f)),
            f2bf(fmaxf(fmaf(di, a.y, b.y), 0.f)),
            f2bf(fmaxf(fmaf(di, a.z, b.z), 0.f)),
            f2bf(fmaxf(fmaf(di, a.w, b.w), 0.f))};
  *(ushort4*)(outp + (size_t)node * 256 + c0) = o;
}

__global__ __launch_bounds__(256) void agg2_kernel(const unsigned char* __restrict__ hn8,
                                                   const float* __restrict__ dinv,
                                                   const int* __restrict__ rowptr,
                                                   const int* __restrict__ csr,
                                                   const float* __restrict__ bias,
                                                   float* __restrict__ partials) {
  __shared__ float sm[1024];
  int wave = threadIdx.x >> 6, lane = threadIdx.x & 63;
  int node = blockIdx.x * 4 + wave;                 // 12500*4 = 50000 exact
  int c0 = lane * 4;
  float4 a = gather_node(hn8, rowptr, csr, node, c0);
  float di = dinv[node];
  float4 b = *(const float4*)(bias + c0);
  sm[wave * 256 + c0 + 0] = fmaxf(fmaf(di, a.x, b.x), 0.f);
  sm[wave * 256 + c0 + 1] = fmaxf(fmaf(di, a.y, b.y), 0.f);
  sm[wave * 256 + c0 + 2] = fmaxf(fmaf(di, a.z, b.z), 0.f);
  sm[wave * 256 + c0 + 3] = fmaxf(fmaf(di, a.w, b.w), 0.f);
  __syncthreads();
  int t = threadIdx.x;
  partials[(size_t)blockIdx.x * 256 + t] = sm[t] + sm[256 + t] + sm[512 + t] + sm[768 + t];
}

// ---------------- readout (R10 verbatim) ----------------
__global__ __launch_bounds__(256) void reduce2_kernel(const float* __restrict__ partials,
                                                      float* __restrict__ p2) {
  int t = threadIdx.x, b = blockIdx.x;              // 64 blocks
  float s = 0.f;
  for (int r = b; r < AGG_BLOCKS; r += RED_BLOCKS) s += partials[(size_t)r * 256 + t];
  p2[b * 256 + t] = s;
}
__global__ __launch_bounds__(256) void final_kernel(const float* __restrict__ p2,
                                                    const float* __restrict__ Wfc,
                                                    const float* __restrict__ bfc,
                                                    float* __restrict__ out) {
  __shared__ float red[256];
  int t = threadIdx.x;
  float s = 0.f;
  for (int b = 0; b < RED_BLOCKS; ++b) s += p2[b * 256 + t];
  float g = s * (1.0f / (float)NODES);
  red[t] = g * Wfc[t];
  __syncthreads();
  for (int off = 128; off > 0; off >>= 1) {
    if (t < off) red[t] += red[t + off];
    __syncthreads();
  }
  if (t == 0) {
    float z = red[0] + bfc[0];
    out[0] = 1.0f / (1.0f + expf(-z));
  }
}

// ---------------- launch ----------------
extern "C" void kernel_launch(void* const* d_in, const int* in_sizes, int n_in,
                              void* d_out, int out_size, void* d_ws, size_t ws_size,
                              hipStream_t stream) {
  (void)in_sizes; (void)n_in; (void)out_size; (void)ws_size;
  const float* x   = (const float*)d_in[0];
  const int*   ei  = (const int*)d_in[1];
  const float* W1  = (const float*)d_in[2];
  const float* b1  = (const float*)d_in[3];
  const float* W2  = (const float*)d_in[4];
  const float* b2  = (const float*)d_in[5];
  const float* Wfc = (const float*)d_in[6];
  const float* bfc = (const float*)d_in[7];
  float* out = (float*)d_out;
  char* ws = (char*)d_ws;

  unsigned char*  hn8  = (unsigned char*)(ws + OFF_HN);
  unsigned short* h1p  = (unsigned short*)(ws + OFF_H1P);
  unsigned short* w1t  = (unsigned short*)(ws + OFF_W1T);
  unsigned short* w2t  = (unsigned short*)(ws + OFF_W2T);
  int*   deg    = (int*)(ws + OFF_DEG);
  int*   fill   = (int*)(ws + OFF_FILL);
  int*   rowptr = (int*)(ws + OFF_ROWP);
  int*   csr    = (int*)(ws + OFF_CSR);
  int*   bsum   = (int*)(ws + OFF_BSUM);
  int*   boff   = (int*)(ws + OFF_BOFF);
  float* part   = (float*)(ws + OFF_PART);
  float* p2     = (float*)(ws + OFF_P2);
  float* dinv   = (float*)(ws + OFF_DINV);

  transw_zero_kernel<<<866, 256, 0, stream>>>(W1, W2, w1t, w2t, (int4*)deg);
  hist_kernel<<<EDGES / 256, 256, 0, stream>>>(ei, deg);
  scan1_kernel<<<NB_SCAN, 256, 0, stream>>>(deg, rowptr, bsum, dinv);
  scan2_kernel<<<1, 256, 0, stream>>>(bsum, boff, rowptr + NODES);
  scan3_kernel<<<NB_SCAN, 256, 0, stream>>>(rowptr, boff);
  fill_kernel<<<EDGES / 256, 256, 0, stream>>>(ei, rowptr, fill, csr);

  gemm1_deep<<<GEMM_MB128, 512, 0, stream>>>(x, w1t, dinv, hn8);
  agg1_kernel<<<AGG_BLOCKS, 256, 0, stream>>>(hn8, dinv, rowptr, csr, b1, h1p);
  gemm2_deep<<<GEMM_MB128, 512, 0, stream>>>(h1p, w2t, dinv, hn8);
  agg2_kernel<<<AGG_BLOCKS, 256, 0, stream>>>(hn8, dinv, rowptr, csr, b2, part);
  reduce2_kernel<<<RED_BLOCKS, 256, 0, stream>>>(part, p2);
  final_kernel<<<1, 256, 0, stream>>>(p2, Wfc, bfc, out);
}

// Round 17
// 270.764 us; speedup vs baseline: 1.6234x; 1.0191x over previous
//
#include <hip/hip_runtime.h>
#include <stdint.h>

#define AS1 __attribute__((address_space(1)))
#define AS3 __attribute__((address_space(3)))

typedef __bf16 bf16x8 __attribute__((ext_vector_type(8)));
typedef float  f32x4  __attribute__((ext_vector_type(4)));
typedef unsigned short u16x8 __attribute__((ext_vector_type(8)));

static constexpr int NODES  = 50000;
static constexpr int EDGES  = 800000;
static constexpr int INDIM  = 512;
static constexpr int HIDDIM = 256;
static constexpr int NB_SCAN = (NODES + 255) / 256;   // 196
static constexpr int AGG_BLOCKS = NODES / 4;          // 12500 (exact)
static constexpr int RED_BLOCKS = 64;
static constexpr int GEMM_MB256 = (NODES + 255) / 256; // 196 row-blocks (BM=256)

// ---------------- ws layout (bytes) — R10's ----------------
static constexpr size_t OFF_PART = 0;            // f32  [12500][256]
static constexpr size_t OFF_HN   = 51200000;     // fp8  [50000][256] pre-scaled h (both layers)
static constexpr size_t OFF_H1P  = 76800000;     // fp8  [50000][256] relu(layer1) output
static constexpr size_t OFF_W1T  = 102400000;    // bf16 [256][512]
static constexpr size_t OFF_W2T8 = 102662144;    // fp8  [256][256]
static constexpr size_t OFF_DEG  = 102793216;    // i32 [50000]
static constexpr size_t OFF_FILL = 102993216;    // i32 [50000]
static constexpr size_t OFF_ROWP = 103193216;    // i32 [50001]
static constexpr size_t OFF_CSR  = 103393280;    // i32 [800000]
static constexpr size_t OFF_BSUM = 106593280;    // i32 [196]
static constexpr size_t OFF_BOFF = 106594304;    // i32 [256]
static constexpr size_t OFF_P2   = 106595840;    // f32 [64][256]
static constexpr size_t OFF_DINV = 106661376;    // f32 [50000]

__device__ __forceinline__ unsigned short f2bf(float f) {
  unsigned u = __builtin_bit_cast(unsigned, f);
  unsigned r = (u + 0x7FFFu + ((u >> 16) & 1u)) >> 16;   // RNE
  return (unsigned short)r;
}
__device__ __forceinline__ unsigned char f2fp8(float f) {
  int p = __builtin_amdgcn_cvt_pk_fp8_f32(f, f, 0, false);   // OCP e4m3fn
  return (unsigned char)(p & 0xff);
}
__device__ __forceinline__ void acc_fp8(float4& a, unsigned u) {
  a.x += __builtin_amdgcn_cvt_f32_fp8(u, 0);
  a.y += __builtin_amdgcn_cvt_f32_fp8(u, 1);
  a.z += __builtin_amdgcn_cvt_f32_fp8(u, 2);
  a.w += __builtin_amdgcn_cvt_f32_fp8(u, 3);
}
__device__ __forceinline__ void gload_lds16(const void* g, void* l) {
  __builtin_amdgcn_global_load_lds((const AS1 void*)g, (AS3 void*)l, 16, 0, 0);
}

// counted-wait primitives (T4)
#define WAITVM(N)  asm volatile("s_waitcnt vmcnt(" #N ")" ::: "memory")
#define WAITLGKM   asm volatile("s_waitcnt lgkmcnt(0)" ::: "memory")
#define HWBARRIER  { asm volatile("" ::: "memory"); __builtin_amdgcn_s_barrier(); \
                     asm volatile("" ::: "memory"); }

// -------- weight prep: W1T bf16, W2T fp8 + scratch zeroing (fused) --------
__global__ __launch_bounds__(256) void transw_zero_kernel(const float* __restrict__ W1,
                                                          const float* __restrict__ W2,
                                                          unsigned short* __restrict__ W1T,
                                                          unsigned char* __restrict__ W2T8,
                                                          int4* __restrict__ zreg) {
  int b = blockIdx.x, tid = threadIdx.x;
  if (b < 512) {                                    // W1T[n][k] = bf16(W1[k][n])
    int t = b * 256 + tid; int n = t >> 9, k = t & 511;
    W1T[t] = f2bf(W1[k * HIDDIM + n]);
  } else if (b < 768) {                             // W2T8[n][k] = fp8(W2[k][n])
    int u = (b - 512) * 256 + tid; int n = u >> 8, k = u & 255;
    W2T8[u] = f2fp8(W2[k * HIDDIM + n]);
  } else {                                          // zero deg+fill (400000 B)
    int i = (b - 768) * 256 + tid;
    if (i < 25000) zreg[i] = int4{0, 0, 0, 0};
  }
}

// ---------------- degree histogram (inline int64-layout detect) ----------------
__global__ __launch_bounds__(256) void hist_kernel(const int* __restrict__ ei,
                                                   int* __restrict__ deg) {
  __shared__ int sflag;
  if (threadIdx.x < 64) {
    unsigned long long b = __ballot(ei[2 * threadIdx.x + 1] == 0);
    if (threadIdx.x == 0) sflag = (b == 0xFFFFFFFFFFFFFFFFull) ? 1 : 0;
  }
  __syncthreads();
  int f = sflag;
  int e = blockIdx.x * 256 + threadIdx.x;        // 3125*256 = 800000 exact
  int d = f ? ei[2 * (EDGES + e)] : ei[EDGES + e];
  atomicAdd(&deg[d], 1);
}

// ---------------- scan (3 kernels) + dinv ----------------
__global__ __launch_bounds__(256) void scan1_kernel(const int* __restrict__ deg,
                                                    int* __restrict__ rowptr,
                                                    int* __restrict__ bsum,
                                                    float* __restrict__ dinv) {
  __shared__ int s[256];
  int t = threadIdx.x, i = blockIdx.x * 256 + t;
  int v = (i < NODES) ? deg[i] : 0;
  if (i < NODES) dinv[i] = rsqrtf((float)(v + 1));   // +1 self-loop
  s[t] = v; __syncthreads();
  for (int off = 1; off < 256; off <<= 1) {
    int x = (t >= off) ? s[t - off] : 0;
    __syncthreads(); s[t] += x; __syncthreads();
  }
  if (i < NODES) rowptr[i] = s[t] - v;
  if (t == 255) bsum[blockIdx.x] = s[255];
}
__global__ __launch_bounds__(256) void scan2_kernel(const int* __restrict__ bsum,
                                                    int* __restrict__ boff,
                                                    int* __restrict__ rowptrN) {
  __shared__ int s[256];
  int t = threadIdx.x;
  int v = (t < NB_SCAN) ? bsum[t] : 0;
  s[t] = v; __syncthreads();
  for (int off = 1; off < 256; off <<= 1) {
    int x = (t >= off) ? s[t - off] : 0;
    __syncthreads(); s[t] += x; __syncthreads();
  }
  if (t < NB_SCAN) boff[t] = s[t] - v;
  if (t == 255) *rowptrN = s[255];
}
__global__ __launch_bounds__(256) void scan3_kernel(int* __restrict__ rowptr,
                                                    const int* __restrict__ boff) {
  int i = blockIdx.x * 256 + threadIdx.x;
  if (i < NODES) rowptr[i] += boff[blockIdx.x];
}

// ---------------- CSR fill (inline detect) ----------------
__global__ __launch_bounds__(256) void fill_kernel(const int* __restrict__ ei,
                                                   const int* __restrict__ rowptr,
                                                   int* __restrict__ fill,
                                                   int* __restrict__ csr) {
  __shared__ int sflag;
  if (threadIdx.x < 64) {
    unsigned long long b = __ballot(ei[2 * threadIdx.x + 1] == 0);
    if (threadIdx.x == 0) sflag = (b == 0xFFFFFFFFFFFFFFFFull) ? 1 : 0;
  }
  __syncthreads();
  int f = sflag;
  int e = blockIdx.x * 256 + threadIdx.x;
  int s, d;
  if (f) { s = ei[2 * e]; d = ei[2 * (EDGES + e)]; }
  else   { s = ei[e];     d = ei[EDGES + e]; }
  int p = atomicAdd(&fill[d], 1);
  csr[rowptr[d] + p] = s;
}

// ------- GEMM1 (R10 verbatim): BM=BN=256, BK=32, counted vmcnt, bf16 MFMA -------
__global__ __launch_bounds__(512, 2) void gemm1_kernel(const float* __restrict__ A,
                                                       const unsigned short* __restrict__ BT,
                                                       const float* __restrict__ dinv,
                                                       unsigned char* __restrict__ Cn8) {
  constexpr int K = INDIM, NSTEP = K / 32;
  __shared__ unsigned short As[2][256 * 32];   // 16 KB per buf
  __shared__ unsigned short Bs[2][256 * 32];   // 16 KB per buf (total 64 KB)
  const int tid = threadIdx.x, wave = tid >> 6, lane = tid & 63;
  const int fr = lane & 15, q = lane >> 4;
  const int wr = wave >> 2, wc = wave & 3;     // 2m x 4n
  const int m0 = blockIdx.x * 256;

  const int lrow4 = lane >> 2;                 // 0..15: row within 16-row slab
  const int sgq   = (lane & 3) ^ (lrow4 & 3);  // pre-swizzled source 16B group

  f32x4 acc[8][4] = {};
  float4 fa[4];                                // fp32 A staging regs

#define STAGE_B(buf, kb)                                                      \
  {                                                                           \
    _Pragma("unroll")                                                         \
    for (int c = 0; c < 2; ++c) {                                             \
      int rbase = wave * 32 + c * 16;                                         \
      int gr = rbase + lrow4;                                                 \
      gload_lds16(BT + (size_t)gr * K + (kb) + sgq * 8, &Bs[buf][rbase * 32]);\
    }                                                                         \
  }
#define LOAD_A32(kb)                                                          \
  {                                                                           \
    _Pragma("unroll")                                                         \
    for (int j = 0; j < 4; ++j) {                                             \
      int F = tid + j * 512;                                                  \
      int r0 = m0 + (F >> 3); if (r0 > NODES - 1) r0 = NODES - 1;             \
      fa[j] = *(const float4*)(A + (size_t)r0 * K + (kb) + (F & 7) * 4);      \
    }                                                                         \
  }
#define WRITE_A32(buf)                                                        \
  {                                                                           \
    _Pragma("unroll")                                                         \
    for (int j = 0; j < 4; ++j) {                                             \
      int F = tid + j * 512;                                                  \
      int row = F >> 3, g4 = F & 7;                                           \
      ushort4 o{f2bf(fa[j].x), f2bf(fa[j].y), f2bf(fa[j].z), f2bf(fa[j].w)};  \
      int col = (((g4 >> 1) ^ (row & 3)) * 8) + (g4 & 1) * 4;                 \
      *(ushort4*)&As[buf][row * 32 + col] = o;                                \
    }                                                                         \
  }

  LOAD_A32(0); WRITE_A32(0); WAITLGKM;
  STAGE_B(0, 0);

  for (int t = 0; t < NSTEP; ++t) {
    const int cur = t & 1, nxt = cur ^ 1;
    if (t + 1 < NSTEP) {
      const int kb1 = (t + 1) * 32;
      LOAD_A32(kb1);
      STAGE_B(nxt, kb1);
      WAITVM(6);
    } else {
      WAITVM(0);
    }
    HWBARRIER;

    bf16x8 af[8], bq[4];
#pragma unroll
    for (int m = 0; m < 8; ++m) {
      int row = wr * 128 + m * 16 + fr;
      af[m] = *(const bf16x8*)&As[cur][row * 32 + ((q ^ (row & 3)) * 8)];
    }
#pragma unroll
    for (int n = 0; n < 4; ++n) {
      int row = wc * 64 + n * 16 + fr;
      bq[n] = *(const bf16x8*)&Bs[cur][row * 32 + ((q ^ (row & 3)) * 8)];
    }
#pragma unroll
    for (int m = 0; m < 8; ++m)
#pragma unroll
      for (int n = 0; n < 4; ++n)
        acc[m][n] = __builtin_amdgcn_mfma_f32_16x16x32_bf16(af[m], bq[n], acc[m][n], 0, 0, 0);

    if (t + 1 < NSTEP) { WRITE_A32(nxt); WAITLGKM; }
    HWBARRIER;
  }
#undef STAGE_B
#undef LOAD_A32
#undef WRITE_A32

  const int rq = q * 4;
#pragma unroll
  for (int m = 0; m < 8; ++m) {
    int rbase = m0 + wr * 128 + m * 16 + rq;
#pragma unroll
    for (int r = 0; r < 4; ++r) {
      int grow = rbase + r;
      if (grow < NODES) {
        float dv = dinv[grow];
#pragma unroll
        for (int n = 0; n < 4; ++n) {
          int gcol = wc * 64 + n * 16 + fr;
          Cn8[(size_t)grow * 256 + gcol] = f2fp8(acc[m][n][r] * dv);
        }
      }
    }
  }
}

// ------- GEMM2 (R12 verbatim): fp8 memory + native fp8 MFMA, BK=64 -------
__global__ __launch_bounds__(512, 2) void gemm2_fp8_kernel(const unsigned char* __restrict__ A8,
                                                           const unsigned char* __restrict__ BT8,
                                                           const float* __restrict__ dinv,
                                                           unsigned char* __restrict__ Cn8) {
  constexpr int K = HIDDIM, NSTEP = K / 64;    // 4
  __shared__ unsigned char As[2][256 * 64];    // 16 KB per buf
  __shared__ unsigned char Bs[2][256 * 64];    // 16 KB per buf (total 64 KB)
  const int tid = threadIdx.x, wave = tid >> 6, lane = tid & 63;
  const int fr = lane & 15, q = lane >> 4;
  const int wr = wave >> 2, wc = wave & 3;     // 2m x 4n
  const int m0 = blockIdx.x * 256;

  const int srl0 = lane >> 2, sch = lane & 3;  // staging: (row lane>>2, 16B grp lane&3)

  f32x4 acc[8][4] = {};

#define STAGE_T(dstArr, buf, srcp, rowbase, kb, CLAMP)                        \
  {                                                                           \
    _Pragma("unroll")                                                         \
    for (int c = 0; c < 2; ++c) {                                             \
      int rl = (wave * 2 + c) * 16 + srl0;                                    \
      int gr = (rowbase) + rl;                                                \
      if (CLAMP) { if (gr > NODES - 1) gr = NODES - 1; }                      \
      const unsigned char* sp = srcp + (size_t)gr * K + (kb) +                \
                                ((sch ^ (rl & 3)) << 4);                      \
      gload_lds16(sp, &dstArr[buf][(wave * 2 + c) * 1024]);                   \
    }                                                                         \
  }

  STAGE_T(As, 0, A8, m0, 0, true);
  STAGE_T(Bs, 0, BT8, 0, 0, false);

  for (int t = 0; t < NSTEP; ++t) {
    const int cur = t & 1, nxt = cur ^ 1;
    if (t + 1 < NSTEP) {
      const int kb1 = (t + 1) * 64;
      STAGE_T(As, nxt, A8, m0, kb1, true);
      STAGE_T(Bs, nxt, BT8, 0, kb1, false);
      WAITVM(4);
    } else {
      WAITVM(0);
    }
    HWBARRIER;

#pragma unroll
    for (int s = 0; s < 2; ++s) {               // two K=32 slabs per step
      long af[8], bq[4];
#pragma unroll
      for (int m = 0; m < 8; ++m) {
        int row = wr * 128 + m * 16 + fr;
        int cch = s * 2 + (q >> 1);
        af[m] = *(const long*)
            &As[cur][row * 64 + ((cch ^ (row & 3)) << 4) + (q & 1) * 8];
      }
#pragma unroll
      for (int n = 0; n < 4; ++n) {
        int row = wc * 64 + n * 16 + fr;
        int cch = s * 2 + (q >> 1);
        bq[n] = *(const long*)
            &Bs[cur][row * 64 + ((cch ^ (row & 3)) << 4) + (q & 1) * 8];
      }
#pragma unroll
      for (int m = 0; m < 8; ++m)
#pragma unroll
        for (int n = 0; n < 4; ++n)
          acc[m][n] = __builtin_amdgcn_mfma_f32_16x16x32_fp8_fp8(af[m], bq[n], acc[m][n], 0, 0, 0);
    }
    HWBARRIER;
  }
#undef STAGE_T

  const int rq = q * 4;
#pragma unroll
  for (int m = 0; m < 8; ++m) {
    int rbase = m0 + wr * 128 + m * 16 + rq;
#pragma unroll
    for (int r = 0; r < 4; ++r) {
      int grow = rbase + r;
      if (grow < NODES) {
        float dv = dinv[grow];
#pragma unroll
        for (int n = 0; n < 4; ++n) {
          int gcol = wc * 64 + n * 16 + fr;
          Cn8[(size_t)grow * 256 + gcol] = f2fp8(acc[m][n][r] * dv);
        }
      }
    }
  }
}

// ---------------- gather core: fp8 rows, unroll-8 (R10 verbatim) ----------------
__device__ __forceinline__ float4 gather_node(const unsigned char* __restrict__ hn8,
                                              const int* __restrict__ rowptr,
                                              const int* __restrict__ csr,
                                              int node, int boff) {
  float4 A{0.f, 0.f, 0.f, 0.f}, B{0.f, 0.f, 0.f, 0.f};
  unsigned us = *(const unsigned*)(hn8 + (size_t)node * 256 + boff);   // self-loop
  acc_fp8(A, us);
  int e0 = rowptr[node], e1 = rowptr[node + 1];
  int e = e0;
  for (; e + 8 <= e1; e += 8) {
    unsigned u0 = *(const unsigned*)(hn8 + (size_t)csr[e + 0] * 256 + boff);
    unsigned u1 = *(const unsigned*)(hn8 + (size_t)csr[e + 1] * 256 + boff);
    unsigned u2 = *(const unsigned*)(hn8 + (size_t)csr[e + 2] * 256 + boff);
    unsigned u3 = *(const unsigned*)(hn8 + (size_t)csr[e + 3] * 256 + boff);
    unsigned u4 = *(const unsigned*)(hn8 + (size_t)csr[e + 4] * 256 + boff);
    unsigned u5 = *(const unsigned*)(hn8 + (size_t)csr[e + 5] * 256 + boff);
    unsigned u6 = *(const unsigned*)(hn8 + (size_t)csr[e + 6] * 256 + boff);
    unsigned u7 = *(const unsigned*)(hn8 + (size_t)csr[e + 7] * 256 + boff);
    acc_fp8(A, u0); acc_fp8(B, u1); acc_fp8(A, u2); acc_fp8(B, u3);
    acc_fp8(A, u4); acc_fp8(B, u5); acc_fp8(A, u6); acc_fp8(B, u7);
  }
  for (; e + 4 <= e1; e += 4) {
    unsigned u0 = *(const unsigned*)(hn8 + (size_t)csr[e + 0] * 256 + boff);
    unsigned u1 = *(const unsigned*)(hn8 + (size_t)csr[e + 1] * 256 + boff);
    unsigned u2 = *(const unsigned*)(hn8 + (size_t)csr[e + 2] * 256 + boff);
    unsigned u3 = *(const unsigned*)(hn8 + (size_t)csr[e + 3] * 256 + boff);
    acc_fp8(A, u0); acc_fp8(B, u1); acc_fp8(A, u2); acc_fp8(B, u3);
  }
  for (; e < e1; ++e) {
    unsigned u = *(const unsigned*)(hn8 + (size_t)csr[e] * 256 + boff);
    acc_fp8(A, u);
  }
  return float4{A.x + B.x, A.y + B.y, A.z + B.z, A.w + B.w};
}

// ---------------- aggregation: agg1 writes fp8 (R12), agg2 -> partials ----------------
__global__ __launch_bounds__(256) void agg1_kernel(const unsigned char* __restrict__ hn8,
                                                   const float* __restrict__ dinv,
                                                   const int* __restrict__ rowptr,
                                                   const int* __restrict__ csr,
                                                   const float* __restrict__ bias,
                                                   unsigned char* __restrict__ h1p8) {
  int wave = threadIdx.x >> 6, lane = threadIdx.x & 63;
  int node = blockIdx.x * 4 + wave;
  int c0 = lane * 4;
  float4 a = gather_node(hn8, rowptr, csr, node, c0);
  float di = dinv[node];
  float4 b = *(const float4*)(bias + c0);
  float r0 = fmaxf(fmaf(di, a.x, b.x), 0.f);
  float r1 = fmaxf(fmaf(di, a.y, b.y), 0.f);
  float r2 = fmaxf(fmaf(di, a.z, b.z), 0.f);
  float r3 = fmaxf(fmaf(di, a.w, b.w), 0.f);
  int p = __builtin_amdgcn_cvt_pk_fp8_f32(r0, r1, 0, false);
  p     = __builtin_amdgcn_cvt_pk_fp8_f32(r2, r3, p, true);
  *(unsigned*)(h1p8 + (size_t)node * 256 + c0) = (unsigned)p;
}

__global__ __launch_bounds__(256) void agg2_kernel(const unsigned char* __restrict__ hn8,
                                                   const float* __restrict__ dinv,
                                                   const int* __restrict__ rowptr,
                                                   const int* __restrict__ csr,
                                                   const float* __restrict__ bias,
                                                   float* __restrict__ partials) {
  __shared__ float sm[1024];
  int wave = threadIdx.x >> 6, lane = threadIdx.x & 63;
  int node = blockIdx.x * 4 + wave;                 // 12500*4 = 50000 exact
  int c0 = lane * 4;
  float4 a = gather_node(hn8, rowptr, csr, node, c0);
  float di = dinv[node];
  float4 b = *(const float4*)(bias + c0);
  sm[wave * 256 + c0 + 0] = fmaxf(fmaf(di, a.x, b.x), 0.f);
  sm[wave * 256 + c0 + 1] = fmaxf(fmaf(di, a.y, b.y), 0.f);
  sm[wave * 256 + c0 + 2] = fmaxf(fmaf(di, a.z, b.z), 0.f);
  sm[wave * 256 + c0 + 3] = fmaxf(fmaf(di, a.w, b.w), 0.f);
  __syncthreads();
  int t = threadIdx.x;
  partials[(size_t)blockIdx.x * 256 + t] = sm[t] + sm[256 + t] + sm[512 + t] + sm[768 + t];
}

// ---------------- readout (R10 verbatim) ----------------
__global__ __launch_bounds__(256) void reduce2_kernel(const float* __restrict__ partials,
                                                      float* __restrict__ p2) {
  int t = threadIdx.x, b = blockIdx.x;              // 64 blocks
  float s = 0.f;
  for (int r = b; r < AGG_BLOCKS; r += RED_BLOCKS) s += partials[(size_t)r * 256 + t];
  p2[b * 256 + t] = s;
}
__global__ __launch_bounds__(256) void final_kernel(const float* __restrict__ p2,
                                                    const float* __restrict__ Wfc,
                                                    const float* __restrict__ bfc,
                                                    float* __restrict__ out) {
  __shared__ float red[256];
  int t = threadIdx.x;
  float s = 0.f;
  for (int b = 0; b < RED_BLOCKS; ++b) s += p2[b * 256 + t];
  float g = s * (1.0f / (float)NODES);
  red[t] = g * Wfc[t];
  __syncthreads();
  for (int off = 128; off > 0; off >>= 1) {
    if (t < off) red[t] += red[t + off];
    __syncthreads();
  }
  if (t == 0) {
    float z = red[0] + bfc[0];
    out[0] = 1.0f / (1.0f + expf(-z));
  }
}

// ---------------- launch ----------------
extern "C" void kernel_launch(void* const* d_in, const int* in_sizes, int n_in,
                              void* d_out, int out_size, void* d_ws, size_t ws_size,
                              hipStream_t stream) {
  (void)in_sizes; (void)n_in; (void)out_size; (void)ws_size;
  const float* x   = (const float*)d_in[0];
  const int*   ei  = (const int*)d_in[1];
  const float* W1  = (const float*)d_in[2];
  const float* b1  = (const float*)d_in[3];
  const float* W2  = (const float*)d_in[4];
  const float* b2  = (const float*)d_in[5];
  const float* Wfc = (const float*)d_in[6];
  const float* bfc = (const float*)d_in[7];
  float* out = (float*)d_out;
  char* ws = (char*)d_ws;

  unsigned char*  hn8  = (unsigned char*)(ws + OFF_HN);
  unsigned char*  h1p8 = (unsigned char*)(ws + OFF_H1P);
  unsigned short* w1t  = (unsigned short*)(ws + OFF_W1T);
  unsigned char*  w2t8 = (unsigned char*)(ws + OFF_W2T8);
  int*   deg    = (int*)(ws + OFF_DEG);
  int*   fill   = (int*)(ws + OFF_FILL);
  int*   rowptr = (int*)(ws + OFF_ROWP);
  int*   csr    = (int*)(ws + OFF_CSR);
  int*   bsum   = (int*)(ws + OFF_BSUM);
  int*   boff   = (int*)(ws + OFF_BOFF);
  float* part   = (float*)(ws + OFF_PART);
  float* p2     = (float*)(ws + OFF_P2);
  float* dinv   = (float*)(ws + OFF_DINV);

  transw_zero_kernel<<<866, 256, 0, stream>>>(W1, W2, w1t, w2t8, (int4*)deg);
  hist_kernel<<<EDGES / 256, 256, 0, stream>>>(ei, deg);
  scan1_kernel<<<NB_SCAN, 256, 0, stream>>>(deg, rowptr, bsum, dinv);
  scan2_kernel<<<1, 256, 0, stream>>>(bsum, boff, rowptr + NODES);
  scan3_kernel<<<NB_SCAN, 256, 0, stream>>>(rowptr, boff);
  fill_kernel<<<EDGES / 256, 256, 0, stream>>>(ei, rowptr, fill, csr);

  gemm1_kernel<<<GEMM_MB256, 512, 0, stream>>>(x, w1t, dinv, hn8);
  agg1_kernel<<<AGG_BLOCKS, 256, 0, stream>>>(hn8, dinv, rowptr, csr, b1, h1p8);
  gemm2_fp8_kernel<<<GEMM_MB256, 512, 0, stream>>>(h1p8, w2t8, dinv, hn8);
  agg2_kernel<<<AGG_BLOCKS, 256, 0, stream>>>(hn8, dinv, rowptr, csr, b2, part);
  reduce2_kernel<<<RED_BLOCKS, 256, 0, stream>>>(part, p2);
  final_kernel<<<1, 256, 0, stream>>>(p2, Wfc, bfc, out);
}

// Round 18
// 268.996 us; speedup vs baseline: 1.6341x; 1.0066x over previous
//
#include <hip/hip_runtime.h>
#include <stdint.h>

#define AS1 __attribute__((address_space(1)))
#define AS3 __attribute__((address_space(3)))

typedef __bf16 bf16x8 __attribute__((ext_vector_type(8)));
typedef float  f32x4  __attribute__((ext_vector_type(4)));

static constexpr int NODES  = 50000;
static constexpr int EDGES  = 800000;
static constexpr int INDIM  = 512;
static constexpr int HIDDIM = 256;
static constexpr int NB_SCAN = (NODES + 255) / 256;   // 196
static constexpr int AGG_BLOCKS = NODES / 4;          // 12500 (exact)
static constexpr int RED_BLOCKS = 64;
static constexpr int GEMM_MB256 = (NODES + 255) / 256; // 196 row-blocks (BM=256)

// ---------------- ws layout (bytes) ----------------
static constexpr size_t OFF_PART = 0;            // f32  [12500][256]
static constexpr size_t OFF_HN   = 51200000;     // fp8  [50000][256] pre-scaled h (both layers)
static constexpr size_t OFF_H1P  = 76800000;     // fp8  [50000][256] relu(layer1) output
static constexpr size_t OFF_W1T  = 102400000;    // bf16 [256][512]
static constexpr size_t OFF_W2T8 = 102662144;    // fp8  [256][256]
static constexpr size_t OFF_DEG  = 102793216;    // i32 [50000]
static constexpr size_t OFF_FILL = 102993216;    // i32 [50000]
static constexpr size_t OFF_ROWP = 103193216;    // i32 [50001]
static constexpr size_t OFF_CSR  = 103393280;    // i32 [800000]
static constexpr size_t OFF_BSUM = 106593280;    // i32 [196]
static constexpr size_t OFF_BOFF = 106594304;    // i32 [256]
static constexpr size_t OFF_P2   = 106595840;    // f32 [64][256]
static constexpr size_t OFF_DINV = 106661376;    // f32 [50000]

__device__ __forceinline__ unsigned short f2bf(float f) {
  unsigned u = __builtin_bit_cast(unsigned, f);
  unsigned r = (u + 0x7FFFu + ((u >> 16) & 1u)) >> 16;   // RNE
  return (unsigned short)r;
}
__device__ __forceinline__ unsigned char f2fp8(float f) {
  int p = __builtin_amdgcn_cvt_pk_fp8_f32(f, f, 0, false);   // OCP e4m3fn
  return (unsigned char)(p & 0xff);
}
__device__ __forceinline__ void acc_fp8(float4& a, unsigned u) {
  a.x += __builtin_amdgcn_cvt_f32_fp8(u, 0);
  a.y += __builtin_amdgcn_cvt_f32_fp8(u, 1);
  a.z += __builtin_amdgcn_cvt_f32_fp8(u, 2);
  a.w += __builtin_amdgcn_cvt_f32_fp8(u, 3);
}
__device__ __forceinline__ void gload_lds16(const void* g, void* l) {
  __builtin_amdgcn_global_load_lds((const AS1 void*)g, (AS3 void*)l, 16, 0, 0);
}

// counted-wait primitives (T4)
#define WAITVM(N)  asm volatile("s_waitcnt vmcnt(" #N ")" ::: "memory")
#define WAITLGKM   asm volatile("s_waitcnt lgkmcnt(0)" ::: "memory")
#define HWBARRIER  { asm volatile("" ::: "memory"); __builtin_amdgcn_s_barrier(); \
                     asm volatile("" ::: "memory"); }

// -------- weight prep: W1T bf16, W2T fp8 + scratch zeroing (fused) --------
__global__ __launch_bounds__(256) void transw_zero_kernel(const float* __restrict__ W1,
                                                          const float* __restrict__ W2,
                                                          unsigned short* __restrict__ W1T,
                                                          unsigned char* __restrict__ W2T8,
                                                          int4* __restrict__ zreg) {
  int b = blockIdx.x, tid = threadIdx.x;
  if (b < 512) {                                    // W1T[n][k] = bf16(W1[k][n])
    int t = b * 256 + tid; int n = t >> 9, k = t & 511;
    W1T[t] = f2bf(W1[k * HIDDIM + n]);
  } else if (b < 768) {                             // W2T8[n][k] = fp8(W2[k][n])
    int u = (b - 512) * 256 + tid; int n = u >> 8, k = u & 255;
    W2T8[u] = f2fp8(W2[k * HIDDIM + n]);
  } else {                                          // zero deg+fill (400000 B)
    int i = (b - 768) * 256 + tid;
    if (i < 25000) zreg[i] = int4{0, 0, 0, 0};
  }
}

// ---------------- degree histogram (inline int64-layout detect) ----------------
__global__ __launch_bounds__(256) void hist_kernel(const int* __restrict__ ei,
                                                   int* __restrict__ deg) {
  __shared__ int sflag;
  if (threadIdx.x < 64) {
    unsigned long long b = __ballot(ei[2 * threadIdx.x + 1] == 0);
    if (threadIdx.x == 0) sflag = (b == 0xFFFFFFFFFFFFFFFFull) ? 1 : 0;
  }
  __syncthreads();
  int f = sflag;
  int e = blockIdx.x * 256 + threadIdx.x;        // 3125*256 = 800000 exact
  int d = f ? ei[2 * (EDGES + e)] : ei[EDGES + e];
  atomicAdd(&deg[d], 1);
}

// ---------------- scan (3 kernels) + dinv ----------------
__global__ __launch_bounds__(256) void scan1_kernel(const int* __restrict__ deg,
                                                    int* __restrict__ rowptr,
                                                    int* __restrict__ bsum,
                                                    float* __restrict__ dinv) {
  __shared__ int s[256];
  int t = threadIdx.x, i = blockIdx.x * 256 + t;
  int v = (i < NODES) ? deg[i] : 0;
  if (i < NODES) dinv[i] = rsqrtf((float)(v + 1));   // +1 self-loop
  s[t] = v; __syncthreads();
  for (int off = 1; off < 256; off <<= 1) {
    int x = (t >= off) ? s[t - off] : 0;
    __syncthreads(); s[t] += x; __syncthreads();
  }
  if (i < NODES) rowptr[i] = s[t] - v;
  if (t == 255) bsum[blockIdx.x] = s[255];
}
__global__ __launch_bounds__(256) void scan2_kernel(const int* __restrict__ bsum,
                                                    int* __restrict__ boff,
                                                    int* __restrict__ rowptrN) {
  __shared__ int s[256];
  int t = threadIdx.x;
  int v = (t < NB_SCAN) ? bsum[t] : 0;
  s[t] = v; __syncthreads();
  for (int off = 1; off < 256; off <<= 1) {
    int x = (t >= off) ? s[t - off] : 0;
    __syncthreads(); s[t] += x; __syncthreads();
  }
  if (t < NB_SCAN) boff[t] = s[t] - v;
  if (t == 255) *rowptrN = s[255];
}
__global__ __launch_bounds__(256) void scan3_kernel(int* __restrict__ rowptr,
                                                    const int* __restrict__ boff) {
  int i = blockIdx.x * 256 + threadIdx.x;
  if (i < NODES) rowptr[i] += boff[blockIdx.x];
}

// ---------------- CSR fill (inline detect) ----------------
__global__ __launch_bounds__(256) void fill_kernel(const int* __restrict__ ei,
                                                   const int* __restrict__ rowptr,
                                                   int* __restrict__ fill,
                                                   int* __restrict__ csr) {
  __shared__ int sflag;
  if (threadIdx.x < 64) {
    unsigned long long b = __ballot(ei[2 * threadIdx.x + 1] == 0);
    if (threadIdx.x == 0) sflag = (b == 0xFFFFFFFFFFFFFFFFull) ? 1 : 0;
  }
  __syncthreads();
  int f = sflag;
  int e = blockIdx.x * 256 + threadIdx.x;
  int s, d;
  if (f) { s = ei[2 * e]; d = ei[2 * (EDGES + e)]; }
  else   { s = ei[e];     d = ei[EDGES + e]; }
  int p = atomicAdd(&fill[d], 1);
  csr[rowptr[d] + p] = s;
}

// ------- GEMM1 (R10 verbatim): BM=BN=256, BK=32, counted vmcnt, bf16 MFMA -------
__global__ __launch_bounds__(512, 2) void gemm1_kernel(const float* __restrict__ A,
                                                       const unsigned short* __restrict__ BT,
                                                       const float* __restrict__ dinv,
                                                       unsigned char* __restrict__ Cn8) {
  constexpr int K = INDIM, NSTEP = K / 32;
  __shared__ unsigned short As[2][256 * 32];   // 16 KB per buf
  __shared__ unsigned short Bs[2][256 * 32];   // 16 KB per buf (total 64 KB)
  const int tid = threadIdx.x, wave = tid >> 6, lane = tid & 63;
  const int fr = lane & 15, q = lane >> 4;
  const int wr = wave >> 2, wc = wave & 3;     // 2m x 4n
  const int m0 = blockIdx.x * 256;

  const int lrow4 = lane >> 2;                 // 0..15: row within 16-row slab
  const int sgq   = (lane & 3) ^ (lrow4 & 3);  // pre-swizzled source 16B group

  f32x4 acc[8][4] = {};
  float4 fa[4];                                // fp32 A staging regs

#define STAGE_B(buf, kb)                                                      \
  {                                                                           \
    _Pragma("unroll")                                                         \
    for (int c = 0; c < 2; ++c) {                                             \
      int rbase = wave * 32 + c * 16;                                         \
      int gr = rbase + lrow4;                                                 \
      gload_lds16(BT + (size_t)gr * K + (kb) + sgq * 8, &Bs[buf][rbase * 32]);\
    }                                                                         \
  }
#define LOAD_A32(kb)                                                          \
  {                                                                           \
    _Pragma("unroll")                                                         \
    for (int j = 0; j < 4; ++j) {                                             \
      int F = tid + j * 512;                                                  \
      int r0 = m0 + (F >> 3); if (r0 > NODES - 1) r0 = NODES - 1;             \
      fa[j] = *(const float4*)(A + (size_t)r0 * K + (kb) + (F & 7) * 4);      \
    }                                                                         \
  }
#define WRITE_A32(buf)                                                        \
  {                                                                           \
    _Pragma("unroll")                                                         \
    for (int j = 0; j < 4; ++j) {                                             \
      int F = tid + j * 512;                                                  \
      int row = F >> 3, g4 = F & 7;                                           \
      ushort4 o{f2bf(fa[j].x), f2bf(fa[j].y), f2bf(fa[j].z), f2bf(fa[j].w)};  \
      int col = (((g4 >> 1) ^ (row & 3)) * 8) + (g4 & 1) * 4;                 \
      *(ushort4*)&As[buf][row * 32 + col] = o;                                \
    }                                                                         \
  }

  LOAD_A32(0); WRITE_A32(0); WAITLGKM;
  STAGE_B(0, 0);

  for (int t = 0; t < NSTEP; ++t) {
    const int cur = t & 1, nxt = cur ^ 1;
    if (t + 1 < NSTEP) {
      const int kb1 = (t + 1) * 32;
      LOAD_A32(kb1);
      STAGE_B(nxt, kb1);
      WAITVM(6);
    } else {
      WAITVM(0);
    }
    HWBARRIER;

    bf16x8 af[8], bq[4];
#pragma unroll
    for (int m = 0; m < 8; ++m) {
      int row = wr * 128 + m * 16 + fr;
      af[m] = *(const bf16x8*)&As[cur][row * 32 + ((q ^ (row & 3)) * 8)];
    }
#pragma unroll
    for (int n = 0; n < 4; ++n) {
      int row = wc * 64 + n * 16 + fr;
      bq[n] = *(const bf16x8*)&Bs[cur][row * 32 + ((q ^ (row & 3)) * 8)];
    }
#pragma unroll
    for (int m = 0; m < 8; ++m)
#pragma unroll
      for (int n = 0; n < 4; ++n)
        acc[m][n] = __builtin_amdgcn_mfma_f32_16x16x32_bf16(af[m], bq[n], acc[m][n], 0, 0, 0);

    if (t + 1 < NSTEP) { WRITE_A32(nxt); WAITLGKM; }
    HWBARRIER;
  }
#undef STAGE_B
#undef LOAD_A32
#undef WRITE_A32

  const int rq = q * 4;
#pragma unroll
  for (int m = 0; m < 8; ++m) {
    int rbase = m0 + wr * 128 + m * 16 + rq;
#pragma unroll
    for (int r = 0; r < 4; ++r) {
      int grow = rbase + r;
      if (grow < NODES) {
        float dv = dinv[grow];
#pragma unroll
        for (int n = 0; n < 4; ++n) {
          int gcol = wc * 64 + n * 16 + fr;
          Cn8[(size_t)grow * 256 + gcol] = f2fp8(acc[m][n][r] * dv);
        }
      }
    }
  }
}

// ------- GEMM2 (R12 verbatim): fp8 memory + native fp8 MFMA, BK=64 -------
__global__ __launch_bounds__(512, 2) void gemm2_fp8_kernel(const unsigned char* __restrict__ A8,
                                                           const unsigned char* __restrict__ BT8,
                                                           const float* __restrict__ dinv,
                                                           unsigned char* __restrict__ Cn8) {
  constexpr int K = HIDDIM, NSTEP = K / 64;    // 4
  __shared__ unsigned char As[2][256 * 64];    // 16 KB per buf
  __shared__ unsigned char Bs[2][256 * 64];    // 16 KB per buf (total 64 KB)
  const int tid = threadIdx.x, wave = tid >> 6, lane = tid & 63;
  const int fr = lane & 15, q = lane >> 4;
  const int wr = wave >> 2, wc = wave & 3;     // 2m x 4n
  const int m0 = blockIdx.x * 256;

  const int srl0 = lane >> 2, sch = lane & 3;  // staging: (row lane>>2, 16B grp lane&3)

  f32x4 acc[8][4] = {};

#define STAGE_T(dstArr, buf, srcp, rowbase, kb, CLAMP)                        \
  {                                                                           \
    _Pragma("unroll")                                                         \
    for (int c = 0; c < 2; ++c) {                                             \
      int rl = (wave * 2 + c) * 16 + srl0;                                    \
      int gr = (rowbase) + rl;                                                \
      if (CLAMP) { if (gr > NODES - 1) gr = NODES - 1; }                      \
      const unsigned char* sp = srcp + (size_t)gr * K + (kb) +                \
                                ((sch ^ (rl & 3)) << 4);                      \
      gload_lds16(sp, &dstArr[buf][(wave * 2 + c) * 1024]);                   \
    }                                                                         \
  }

  STAGE_T(As, 0, A8, m0, 0, true);
  STAGE_T(Bs, 0, BT8, 0, 0, false);

  for (int t = 0; t < NSTEP; ++t) {
    const int cur = t & 1, nxt = cur ^ 1;
    if (t + 1 < NSTEP) {
      const int kb1 = (t + 1) * 64;
      STAGE_T(As, nxt, A8, m0, kb1, true);
      STAGE_T(Bs, nxt, BT8, 0, kb1, false);
      WAITVM(4);
    } else {
      WAITVM(0);
    }
    HWBARRIER;

#pragma unroll
    for (int s = 0; s < 2; ++s) {               // two K=32 slabs per step
      long af[8], bq[4];
#pragma unroll
      for (int m = 0; m < 8; ++m) {
        int row = wr * 128 + m * 16 + fr;
        int cch = s * 2 + (q >> 1);
        af[m] = *(const long*)
            &As[cur][row * 64 + ((cch ^ (row & 3)) << 4) + (q & 1) * 8];
      }
#pragma unroll
      for (int n = 0; n < 4; ++n) {
        int row = wc * 64 + n * 16 + fr;
        int cch = s * 2 + (q >> 1);
        bq[n] = *(const long*)
            &Bs[cur][row * 64 + ((cch ^ (row & 3)) << 4) + (q & 1) * 8];
      }
#pragma unroll
      for (int m = 0; m < 8; ++m)
#pragma unroll
        for (int n = 0; n < 4; ++n)
          acc[m][n] = __builtin_amdgcn_mfma_f32_16x16x32_fp8_fp8(af[m], bq[n], acc[m][n], 0, 0, 0);
    }
    HWBARRIER;
  }
#undef STAGE_T

  const int rq = q * 4;
#pragma unroll
  for (int m = 0; m < 8; ++m) {
    int rbase = m0 + wr * 128 + m * 16 + rq;
#pragma unroll
    for (int r = 0; r < 4; ++r) {
      int grow = rbase + r;
      if (grow < NODES) {
        float dv = dinv[grow];
#pragma unroll
        for (int n = 0; n < 4; ++n) {
          int gcol = wc * 64 + n * 16 + fr;
          Cn8[(size_t)grow * 256 + gcol] = f2fp8(acc[m][n][r] * dv);
        }
      }
    }
  }
}

// --- gather core: SGPR-uniform csr indices (readfirstlane -> s_load batches),
//     unroll-16 top level (16 payload loads in flight), 8/4/scalar tails ---
__device__ __forceinline__ float4 gather_node(const unsigned char* __restrict__ hn8,
                                              const int* __restrict__ rowptr,
                                              const int* __restrict__ csr,
                                              int node, int boff) {
  float4 A{0.f, 0.f, 0.f, 0.f}, B{0.f, 0.f, 0.f, 0.f};
  acc_fp8(A, *(const unsigned*)(hn8 + (size_t)node * 256 + boff));   // self-loop
  // node is wave-uniform; force e0/cnt into SGPRs so csr index loads become
  // scalar (s_load) batches instead of per-lane VMEM broadcasts.
  int e0  = __builtin_amdgcn_readfirstlane(rowptr[node]);
  int cnt = __builtin_amdgcn_readfirstlane(rowptr[node + 1]) - e0;
  const int* cp = csr + e0;
  int i = 0;
  for (; i + 16 <= cnt; i += 16) {
    unsigned v[16];
#pragma unroll
    for (int j = 0; j < 16; ++j)
      v[j] = *(const unsigned*)(hn8 + (size_t)cp[i + j] * 256 + boff);
#pragma unroll
    for (int j = 0; j < 16; j += 2) { acc_fp8(A, v[j]); acc_fp8(B, v[j + 1]); }
  }
  for (; i + 8 <= cnt; i += 8) {
    unsigned v[8];
#pragma unroll
    for (int j = 0; j < 8; ++j)
      v[j] = *(const unsigned*)(hn8 + (size_t)cp[i + j] * 256 + boff);
#pragma unroll
    for (int j = 0; j < 8; j += 2) { acc_fp8(A, v[j]); acc_fp8(B, v[j + 1]); }
  }
  for (; i + 4 <= cnt; i += 4) {
    unsigned v[4];
#pragma unroll
    for (int j = 0; j < 4; ++j)
      v[j] = *(const unsigned*)(hn8 + (size_t)cp[i + j] * 256 + boff);
    acc_fp8(A, v[0]); acc_fp8(B, v[1]); acc_fp8(A, v[2]); acc_fp8(B, v[3]);
  }
  for (; i < cnt; ++i)
    acc_fp8(A, *(const unsigned*)(hn8 + (size_t)cp[i] * 256 + boff));
  return float4{A.x + B.x, A.y + B.y, A.z + B.z, A.w + B.w};
}

// ---------------- aggregation: agg1 writes fp8, agg2 -> partials ----------------
__global__ __launch_bounds__(256) void agg1_kernel(const unsigned char* __restrict__ hn8,
                                                   const float* __restrict__ dinv,
                                                   const int* __restrict__ rowptr,
                                                   const int* __restrict__ csr,
                                                   const float* __restrict__ bias,
                                                   unsigned char* __restrict__ h1p8) {
  int wave = threadIdx.x >> 6, lane = threadIdx.x & 63;
  int node = blockIdx.x * 4 + wave;
  int c0 = lane * 4;
  float4 a = gather_node(hn8, rowptr, csr, node, c0);
  float di = dinv[node];
  float4 b = *(const float4*)(bias + c0);
  float r0 = fmaxf(fmaf(di, a.x, b.x), 0.f);
  float r1 = fmaxf(fmaf(di, a.y, b.y), 0.f);
  float r2 = fmaxf(fmaf(di, a.z, b.z), 0.f);
  float r3 = fmaxf(fmaf(di, a.w, b.w), 0.f);
  int p = __builtin_amdgcn_cvt_pk_fp8_f32(r0, r1, 0, false);
  p     = __builtin_amdgcn_cvt_pk_fp8_f32(r2, r3, p, true);
  *(unsigned*)(h1p8 + (size_t)node * 256 + c0) = (unsigned)p;
}

__global__ __launch_bounds__(256) void agg2_kernel(const unsigned char* __restrict__ hn8,
                                                   const float* __restrict__ dinv,
                                                   const int* __restrict__ rowptr,
                                                   const int* __restrict__ csr,
                                                   const float* __restrict__ bias,
                                                   float* __restrict__ partials) {
  __shared__ float sm[1024];
  int wave = threadIdx.x >> 6, lane = threadIdx.x & 63;
  int node = blockIdx.x * 4 + wave;                 // 12500*4 = 50000 exact
  int c0 = lane * 4;
  float4 a = gather_node(hn8, rowptr, csr, node, c0);
  float di = dinv[node];
  float4 b = *(const float4*)(bias + c0);
  sm[wave * 256 + c0 + 0] = fmaxf(fmaf(di, a.x, b.x), 0.f);
  sm[wave * 256 + c0 + 1] = fmaxf(fmaf(di, a.y, b.y), 0.f);
  sm[wave * 256 + c0 + 2] = fmaxf(fmaf(di, a.z, b.z), 0.f);
  sm[wave * 256 + c0 + 3] = fmaxf(fmaf(di, a.w, b.w), 0.f);
  __syncthreads();
  int t = threadIdx.x;
  partials[(size_t)blockIdx.x * 256 + t] = sm[t] + sm[256 + t] + sm[512 + t] + sm[768 + t];
}

// ---------------- readout ----------------
__global__ __launch_bounds__(256) void reduce2_kernel(const float* __restrict__ partials,
                                                      float* __restrict__ p2) {
  int t = threadIdx.x, b = blockIdx.x;              // 64 blocks
  float s = 0.f;
  for (int r = b; r < AGG_BLOCKS; r += RED_BLOCKS) s += partials[(size_t)r * 256 + t];
  p2[b * 256 + t] = s;
}
__global__ __launch_bounds__(256) void final_kernel(const float* __restrict__ p2,
                                                    const float* __restrict__ Wfc,
                                                    const float* __restrict__ bfc,
                                                    float* __restrict__ out) {
  __shared__ float red[256];
  int t = threadIdx.x;
  float s = 0.f;
  for (int b = 0; b < RED_BLOCKS; ++b) s += p2[b * 256 + t];
  float g = s * (1.0f / (float)NODES);
  red[t] = g * Wfc[t];
  __syncthreads();
  for (int off = 128; off > 0; off >>= 1) {
    if (t < off) red[t] += red[t + off];
    __syncthreads();
  }
  if (t == 0) {
    float z = red[0] + bfc[0];
    out[0] = 1.0f / (1.0f + expf(-z));
  }
}

// ---------------- launch ----------------
extern "C" void kernel_launch(void* const* d_in, const int* in_sizes, int n_in,
                              void* d_out, int out_size, void* d_ws, size_t ws_size,
                              hipStream_t stream) {
  (void)in_sizes; (void)n_in; (void)out_size; (void)ws_size;
  const float* x   = (const float*)d_in[0];
  const int*   ei  = (const int*)d_in[1];
  const float* W1  = (const float*)d_in[2];
  const float* b1  = (const float*)d_in[3];
  const float* W2  = (const float*)d_in[4];
  const float* b2  = (const float*)d_in[5];
  const float* Wfc = (const float*)d_in[6];
  const float* bfc = (const float*)d_in[7];
  float* out = (float*)d_out;
  char* ws = (char*)d_ws;

  unsigned char*  hn8  = (unsigned char*)(ws + OFF_HN);
  unsigned char*  h1p8 = (unsigned char*)(ws + OFF_H1P);
  unsigned short* w1t  = (unsigned short*)(ws + OFF_W1T);
  unsigned char*  w2t8 = (unsigned char*)(ws + OFF_W2T8);
  int*   deg    = (int*)(ws + OFF_DEG);
  int*   fill   = (int*)(ws + OFF_FILL);
  int*   rowptr = (int*)(ws + OFF_ROWP);
  int*   csr    = (int*)(ws + OFF_CSR);
  int*   bsum   = (int*)(ws + OFF_BSUM);
  int*   boff   = (int*)(ws + OFF_BOFF);
  float* part   = (float*)(ws + OFF_PART);
  float* p2     = (float*)(ws + OFF_P2);
  float* dinv   = (float*)(ws + OFF_DINV);

  transw_zero_kernel<<<866, 256, 0, stream>>>(W1, W2, w1t, w2t8, (int4*)deg);
  hist_kernel<<<EDGES / 256, 256, 0, stream>>>(ei, deg);
  scan1_kernel<<<NB_SCAN, 256, 0, stream>>>(deg, rowptr, bsum, dinv);
  scan2_kernel<<<1, 256, 0, stream>>>(bsum, boff, rowptr + NODES);
  scan3_kernel<<<NB_SCAN, 256, 0, stream>>>(rowptr, boff);
  fill_kernel<<<EDGES / 256, 256, 0, stream>>>(ei, rowptr, fill, csr);

  gemm1_kernel<<<GEMM_MB256, 512, 0, stream>>>(x, w1t, dinv, hn8);
  agg1_kernel<<<AGG_BLOCKS, 256, 0, stream>>>(hn8, dinv, rowptr, csr, b1, h1p8);
  gemm2_fp8_kernel<<<GEMM_MB256, 512, 0, stream>>>(h1p8, w2t8, dinv, hn8);
  agg2_kernel<<<AGG_BLOCKS, 256, 0, stream>>>(hn8, dinv, rowptr, csr, b2, part);
  reduce2_kernel<<<RED_BLOCKS, 256, 0, stream>>>(part, p2);
  final_kernel<<<1, 256, 0, stream>>>(p2, Wfc, bfc, out);
}

// Round 19
// 258.532 us; speedup vs baseline: 1.7002x; 1.0405x over previous
//
#include <hip/hip_runtime.h>
#include <stdint.h>

#define AS1 __attribute__((address_space(1)))
#define AS3 __attribute__((address_space(3)))

typedef __bf16 bf16x8 __attribute__((ext_vector_type(8)));
typedef float  f32x4  __attribute__((ext_vector_type(4)));

static constexpr int NODES  = 50000;
static constexpr int EDGES  = 800000;
static constexpr int INDIM  = 512;
static constexpr int HIDDIM = 256;
static constexpr int NB_SCAN = (NODES + 255) / 256;   // 196
static constexpr int AGG_BLOCKS = NODES / 4;          // 12500 (exact)
static constexpr int RED_BLOCKS = 64;
static constexpr int GEMM_MB256 = (NODES + 255) / 256; // 196 row-blocks (BM=256)

// ---------------- ws layout (bytes) ----------------
static constexpr size_t OFF_PART = 0;            // f32  [12500][256]
static constexpr size_t OFF_HN   = 51200000;     // fp8  [50000][256] pre-scaled h (both layers)
static constexpr size_t OFF_H1P  = 76800000;     // fp8  [50000][256] relu(layer1) output
static constexpr size_t OFF_W1T  = 102400000;    // bf16 [256][512]
static constexpr size_t OFF_W2T8 = 102662144;    // fp8  [256][256]
static constexpr size_t OFF_DEG  = 102793216;    // i32 [50000]
static constexpr size_t OFF_FILL = 102993216;    // i32 [50000]
static constexpr size_t OFF_ROWP = 103193216;    // i32 [50001]
static constexpr size_t OFF_CSR  = 103393280;    // i32 [800000]
static constexpr size_t OFF_BSUM = 106593280;    // i32 [196]
static constexpr size_t OFF_BOFF = 106594304;    // i32 [256]
static constexpr size_t OFF_P2   = 106595840;    // f32 [64][256]
static constexpr size_t OFF_DINV = 106661376;    // f32 [50000]

__device__ __forceinline__ unsigned short f2bf(float f) {
  unsigned u = __builtin_bit_cast(unsigned, f);
  unsigned r = (u + 0x7FFFu + ((u >> 16) & 1u)) >> 16;   // RNE
  return (unsigned short)r;
}
__device__ __forceinline__ unsigned char f2fp8(float f) {
  int p = __builtin_amdgcn_cvt_pk_fp8_f32(f, f, 0, false);   // OCP e4m3fn
  return (unsigned char)(p & 0xff);
}
__device__ __forceinline__ void acc_fp8(float4& a, unsigned u) {
  a.x += __builtin_amdgcn_cvt_f32_fp8(u, 0);
  a.y += __builtin_amdgcn_cvt_f32_fp8(u, 1);
  a.z += __builtin_amdgcn_cvt_f32_fp8(u, 2);
  a.w += __builtin_amdgcn_cvt_f32_fp8(u, 3);
}
__device__ __forceinline__ void gload_lds16(const void* g, void* l) {
  __builtin_amdgcn_global_load_lds((const AS1 void*)g, (AS3 void*)l, 16, 0, 0);
}

// counted-wait primitives (T4)
#define WAITVM(N)  asm volatile("s_waitcnt vmcnt(" #N ")" ::: "memory")
#define WAITLGKM   asm volatile("s_waitcnt lgkmcnt(0)" ::: "memory")
#define HWBARRIER  { asm volatile("" ::: "memory"); __builtin_amdgcn_s_barrier(); \
                     asm volatile("" ::: "memory"); }

// ---- LDS-bounce epilogue (shared by both gemms): byte-writes to swizzled
// LDS (staging bufs are dead after the K-loop), barrier, coalesced dwordx4
// global stores. Replaces 128 scattered global byte-stores/thread with
// 8 fully-coalesced 16B stores/thread. Chunk-XOR swizzle keeps LDS byte
// writes at ~2-way bank aliasing (free per m136).
#define BOUNCE_EPILOGUE                                                       \
  {                                                                           \
    char* Lb = SMEM;                                                          \
    const int rq = q * 4;                                                     \
    _Pragma("unroll")                                                         \
    for (int m = 0; m < 8; ++m) {                                             \
      _Pragma("unroll")                                                       \
      for (int r = 0; r < 4; ++r) {                                           \
        int rt = wr * 128 + m * 16 + rq + r;                                  \
        int grow = m0 + rt;                                                   \
        if (grow < NODES) {                                                   \
          float dv = dinv[grow];                                              \
          _Pragma("unroll")                                                   \
          for (int n = 0; n < 4; ++n) {                                       \
            int ch = (wc * 4 + n) ^ (rt & 15);                                \
            Lb[rt * 256 + ch * 16 + fr] = (char)f2fp8(acc[m][n][r] * dv);     \
          }                                                                   \
        }                                                                     \
      }                                                                       \
    }                                                                         \
    HWBARRIER;                                                                \
    _Pragma("unroll")                                                         \
    for (int p = 0; p < 8; ++p) {                                             \
      int idx = p * 512 + tid;              /* 0..4095: (row, 16B seg) */     \
      int rt = idx >> 4, seg = idx & 15;                                      \
      int grow = m0 + rt;                                                     \
      if (grow < NODES)                                                       \
        *(uint4*)(Cn8 + (size_t)grow * 256 + seg * 16) =                      \
            *(const uint4*)(Lb + rt * 256 + ((seg ^ (rt & 15)) * 16));        \
    }                                                                         \
  }

// -------- weight prep: W1T bf16, W2T fp8 + scratch zeroing (fused) --------
__global__ __launch_bounds__(256) void transw_zero_kernel(const float* __restrict__ W1,
                                                          const float* __restrict__ W2,
                                                          unsigned short* __restrict__ W1T,
                                                          unsigned char* __restrict__ W2T8,
                                                          int4* __restrict__ zreg) {
  int b = blockIdx.x, tid = threadIdx.x;
  if (b < 512) {                                    // W1T[n][k] = bf16(W1[k][n])
    int t = b * 256 + tid; int n = t >> 9, k = t & 511;
    W1T[t] = f2bf(W1[k * HIDDIM + n]);
  } else if (b < 768) {                             // W2T8[n][k] = fp8(W2[k][n])
    int u = (b - 512) * 256 + tid; int n = u >> 8, k = u & 255;
    W2T8[u] = f2fp8(W2[k * HIDDIM + n]);
  } else {                                          // zero deg+fill (400000 B)
    int i = (b - 768) * 256 + tid;
    if (i < 25000) zreg[i] = int4{0, 0, 0, 0};
  }
}

// ---------------- degree histogram (inline int64-layout detect) ----------------
__global__ __launch_bounds__(256) void hist_kernel(const int* __restrict__ ei,
                                                   int* __restrict__ deg) {
  __shared__ int sflag;
  if (threadIdx.x < 64) {
    unsigned long long b = __ballot(ei[2 * threadIdx.x + 1] == 0);
    if (threadIdx.x == 0) sflag = (b == 0xFFFFFFFFFFFFFFFFull) ? 1 : 0;
  }
  __syncthreads();
  int f = sflag;
  int e = blockIdx.x * 256 + threadIdx.x;        // 3125*256 = 800000 exact
  int d = f ? ei[2 * (EDGES + e)] : ei[EDGES + e];
  atomicAdd(&deg[d], 1);
}

// ---------------- scan (3 kernels) + dinv ----------------
__global__ __launch_bounds__(256) void scan1_kernel(const int* __restrict__ deg,
                                                    int* __restrict__ rowptr,
                                                    int* __restrict__ bsum,
                                                    float* __restrict__ dinv) {
  __shared__ int s[256];
  int t = threadIdx.x, i = blockIdx.x * 256 + t;
  int v = (i < NODES) ? deg[i] : 0;
  if (i < NODES) dinv[i] = rsqrtf((float)(v + 1));   // +1 self-loop
  s[t] = v; __syncthreads();
  for (int off = 1; off < 256; off <<= 1) {
    int x = (t >= off) ? s[t - off] : 0;
    __syncthreads(); s[t] += x; __syncthreads();
  }
  if (i < NODES) rowptr[i] = s[t] - v;
  if (t == 255) bsum[blockIdx.x] = s[255];
}
__global__ __launch_bounds__(256) void scan2_kernel(const int* __restrict__ bsum,
                                                    int* __restrict__ boff,
                                                    int* __restrict__ rowptrN) {
  __shared__ int s[256];
  int t = threadIdx.x;
  int v = (t < NB_SCAN) ? bsum[t] : 0;
  s[t] = v; __syncthreads();
  for (int off = 1; off < 256; off <<= 1) {
    int x = (t >= off) ? s[t - off] : 0;
    __syncthreads(); s[t] += x; __syncthreads();
  }
  if (t < NB_SCAN) boff[t] = s[t] - v;
  if (t == 255) *rowptrN = s[255];
}
__global__ __launch_bounds__(256) void scan3_kernel(int* __restrict__ rowptr,
                                                    const int* __restrict__ boff) {
  int i = blockIdx.x * 256 + threadIdx.x;
  if (i < NODES) rowptr[i] += boff[blockIdx.x];
}

// ---------------- CSR fill (inline detect) ----------------
__global__ __launch_bounds__(256) void fill_kernel(const int* __restrict__ ei,
                                                   const int* __restrict__ rowptr,
                                                   int* __restrict__ fill,
                                                   int* __restrict__ csr) {
  __shared__ int sflag;
  if (threadIdx.x < 64) {
    unsigned long long b = __ballot(ei[2 * threadIdx.x + 1] == 0);
    if (threadIdx.x == 0) sflag = (b == 0xFFFFFFFFFFFFFFFFull) ? 1 : 0;
  }
  __syncthreads();
  int f = sflag;
  int e = blockIdx.x * 256 + threadIdx.x;
  int s, d;
  if (f) { s = ei[2 * e]; d = ei[2 * (EDGES + e)]; }
  else   { s = ei[e];     d = ei[EDGES + e]; }
  int p = atomicAdd(&fill[d], 1);
  csr[rowptr[d] + p] = s;
}

// ------- GEMM1: BM=BN=256, BK=32, counted vmcnt, bf16 MFMA, bounce epilogue -------
__global__ __launch_bounds__(512, 2) void gemm1_kernel(const float* __restrict__ A,
                                                       const unsigned short* __restrict__ BT,
                                                       const float* __restrict__ dinv,
                                                       unsigned char* __restrict__ Cn8) {
  constexpr int K = INDIM, NSTEP = K / 32;
  __shared__ char SMEM[65536];
  unsigned short (*As)[8192] = (unsigned short (*)[8192])SMEM;          // 2x16KB
  unsigned short (*Bs)[8192] = (unsigned short (*)[8192])(SMEM + 32768);// 2x16KB
  const int tid = threadIdx.x, wave = tid >> 6, lane = tid & 63;
  const int fr = lane & 15, q = lane >> 4;
  const int wr = wave >> 2, wc = wave & 3;     // 2m x 4n
  const int m0 = blockIdx.x * 256;

  const int lrow4 = lane >> 2;                 // 0..15: row within 16-row slab
  const int sgq   = (lane & 3) ^ (lrow4 & 3);  // pre-swizzled source 16B group

  f32x4 acc[8][4] = {};
  float4 fa[4];                                // fp32 A staging regs

#define STAGE_B(buf, kb)                                                      \
  {                                                                           \
    _Pragma("unroll")                                                         \
    for (int c = 0; c < 2; ++c) {                                             \
      int rbase = wave * 32 + c * 16;                                         \
      int gr = rbase + lrow4;                                                 \
      gload_lds16(BT + (size_t)gr * K + (kb) + sgq * 8, &Bs[buf][rbase * 32]);\
    }                                                                         \
  }
#define LOAD_A32(kb)                                                          \
  {                                                                           \
    _Pragma("unroll")                                                         \
    for (int j = 0; j < 4; ++j) {                                             \
      int F = tid + j * 512;                                                  \
      int r0 = m0 + (F >> 3); if (r0 > NODES - 1) r0 = NODES - 1;             \
      fa[j] = *(const float4*)(A + (size_t)r0 * K + (kb) + (F & 7) * 4);      \
    }                                                                         \
  }
#define WRITE_A32(buf)                                                        \
  {                                                                           \
    _Pragma("unroll")                                                         \
    for (int j = 0; j < 4; ++j) {                                             \
      int F = tid + j * 512;                                                  \
      int row = F >> 3, g4 = F & 7;                                           \
      ushort4 o{f2bf(fa[j].x), f2bf(fa[j].y), f2bf(fa[j].z), f2bf(fa[j].w)};  \
      int col = (((g4 >> 1) ^ (row & 3)) * 8) + (g4 & 1) * 4;                 \
      *(ushort4*)&As[buf][row * 32 + col] = o;                                \
    }                                                                         \
  }

  LOAD_A32(0); WRITE_A32(0); WAITLGKM;
  STAGE_B(0, 0);

  for (int t = 0; t < NSTEP; ++t) {
    const int cur = t & 1, nxt = cur ^ 1;
    if (t + 1 < NSTEP) {
      const int kb1 = (t + 1) * 32;
      LOAD_A32(kb1);
      STAGE_B(nxt, kb1);
      WAITVM(6);
    } else {
      WAITVM(0);
    }
    HWBARRIER;

    bf16x8 af[8], bq[4];
#pragma unroll
    for (int m = 0; m < 8; ++m) {
      int row = wr * 128 + m * 16 + fr;
      af[m] = *(const bf16x8*)&As[cur][row * 32 + ((q ^ (row & 3)) * 8)];
    }
#pragma unroll
    for (int n = 0; n < 4; ++n) {
      int row = wc * 64 + n * 16 + fr;
      bq[n] = *(const bf16x8*)&Bs[cur][row * 32 + ((q ^ (row & 3)) * 8)];
    }
#pragma unroll
    for (int m = 0; m < 8; ++m)
#pragma unroll
      for (int n = 0; n < 4; ++n)
        acc[m][n] = __builtin_amdgcn_mfma_f32_16x16x32_bf16(af[m], bq[n], acc[m][n], 0, 0, 0);

    if (t + 1 < NSTEP) { WRITE_A32(nxt); WAITLGKM; }
    HWBARRIER;
  }
#undef STAGE_B
#undef LOAD_A32
#undef WRITE_A32

  BOUNCE_EPILOGUE;
}

// ------- GEMM2: fp8 memory + native fp8 MFMA, BK=64, bounce epilogue -------
__global__ __launch_bounds__(512, 2) void gemm2_fp8_kernel(const unsigned char* __restrict__ A8,
                                                           const unsigned char* __restrict__ BT8,
                                                           const float* __restrict__ dinv,
                                                           unsigned char* __restrict__ Cn8) {
  constexpr int K = HIDDIM, NSTEP = K / 64;    // 4
  __shared__ char SMEM[65536];
  unsigned char (*As)[16384] = (unsigned char (*)[16384])SMEM;           // 2x16KB
  unsigned char (*Bs)[16384] = (unsigned char (*)[16384])(SMEM + 32768); // 2x16KB
  const int tid = threadIdx.x, wave = tid >> 6, lane = tid & 63;
  const int fr = lane & 15, q = lane >> 4;
  const int wr = wave >> 2, wc = wave & 3;     // 2m x 4n
  const int m0 = blockIdx.x * 256;

  const int srl0 = lane >> 2, sch = lane & 3;  // staging: (row lane>>2, 16B grp lane&3)

  f32x4 acc[8][4] = {};

#define STAGE_T(dstArr, buf, srcp, rowbase, kb, CLAMP)                        \
  {                                                                           \
    _Pragma("unroll")                                                         \
    for (int c = 0; c < 2; ++c) {                                             \
      int rl = (wave * 2 + c) * 16 + srl0;                                    \
      int gr = (rowbase) + rl;                                                \
      if (CLAMP) { if (gr > NODES - 1) gr = NODES - 1; }                      \
      const unsigned char* sp = srcp + (size_t)gr * K + (kb) +                \
                                ((sch ^ (rl & 3)) << 4);                      \
      gload_lds16(sp, &dstArr[buf][(wave * 2 + c) * 1024]);                   \
    }                                                                         \
  }

  STAGE_T(As, 0, A8, m0, 0, true);
  STAGE_T(Bs, 0, BT8, 0, 0, false);

  for (int t = 0; t < NSTEP; ++t) {
    const int cur = t & 1, nxt = cur ^ 1;
    if (t + 1 < NSTEP) {
      const int kb1 = (t + 1) * 64;
      STAGE_T(As, nxt, A8, m0, kb1, true);
      STAGE_T(Bs, nxt, BT8, 0, kb1, false);
      WAITVM(4);
    } else {
      WAITVM(0);
    }
    HWBARRIER;

#pragma unroll
    for (int s = 0; s < 2; ++s) {               // two K=32 slabs per step
      long af[8], bq[4];
#pragma unroll
      for (int m = 0; m < 8; ++m) {
        int row = wr * 128 + m * 16 + fr;
        int cch = s * 2 + (q >> 1);
        af[m] = *(const long*)
            &As[cur][row * 64 + ((cch ^ (row & 3)) << 4) + (q & 1) * 8];
      }
#pragma unroll
      for (int n = 0; n < 4; ++n) {
        int row = wc * 64 + n * 16 + fr;
        int cch = s * 2 + (q >> 1);
        bq[n] = *(const long*)
            &Bs[cur][row * 64 + ((cch ^ (row & 3)) << 4) + (q & 1) * 8];
      }
#pragma unroll
      for (int m = 0; m < 8; ++m)
#pragma unroll
        for (int n = 0; n < 4; ++n)
          acc[m][n] = __builtin_amdgcn_mfma_f32_16x16x32_fp8_fp8(af[m], bq[n], acc[m][n], 0, 0, 0);
    }
    HWBARRIER;
  }
#undef STAGE_T

  BOUNCE_EPILOGUE;
}

// --- gather core: SGPR-uniform csr indices, unroll-16/8/4/scalar (R18) ---
__device__ __forceinline__ float4 gather_node(const unsigned char* __restrict__ hn8,
                                              const int* __restrict__ rowptr,
                                              const int* __restrict__ csr,
                                              int node, int boff) {
  float4 A{0.f, 0.f, 0.f, 0.f}, B{0.f, 0.f, 0.f, 0.f};
  acc_fp8(A, *(const unsigned*)(hn8 + (size_t)node * 256 + boff));   // self-loop
  int e0  = __builtin_amdgcn_readfirstlane(rowptr[node]);
  int cnt = __builtin_amdgcn_readfirstlane(rowptr[node + 1]) - e0;
  const int* cp = csr + e0;
  int i = 0;
  for (; i + 16 <= cnt; i += 16) {
    unsigned v[16];
#pragma unroll
    for (int j = 0; j < 16; ++j)
      v[j] = *(const unsigned*)(hn8 + (size_t)cp[i + j] * 256 + boff);
#pragma unroll
    for (int j = 0; j < 16; j += 2) { acc_fp8(A, v[j]); acc_fp8(B, v[j + 1]); }
  }
  for (; i + 8 <= cnt; i += 8) {
    unsigned v[8];
#pragma unroll
    for (int j = 0; j < 8; ++j)
      v[j] = *(const unsigned*)(hn8 + (size_t)cp[i + j] * 256 + boff);
#pragma unroll
    for (int j = 0; j < 8; j += 2) { acc_fp8(A, v[j]); acc_fp8(B, v[j + 1]); }
  }
  for (; i + 4 <= cnt; i += 4) {
    unsigned v[4];
#pragma unroll
    for (int j = 0; j < 4; ++j)
      v[j] = *(const unsigned*)(hn8 + (size_t)cp[i + j] * 256 + boff);
    acc_fp8(A, v[0]); acc_fp8(B, v[1]); acc_fp8(A, v[2]); acc_fp8(B, v[3]);
  }
  for (; i < cnt; ++i)
    acc_fp8(A, *(const unsigned*)(hn8 + (size_t)cp[i] * 256 + boff));
  return float4{A.x + B.x, A.y + B.y, A.z + B.z, A.w + B.w};
}

// ---------------- aggregation: agg1 writes fp8, agg2 -> partials ----------------
__global__ __launch_bounds__(256) void agg1_kernel(const unsigned char* __restrict__ hn8,
                                                   const float* __restrict__ dinv,
                                                   const int* __restrict__ rowptr,
                                                   const int* __restrict__ csr,
                                                   const float* __restrict__ bias,
                                                   unsigned char* __restrict__ h1p8) {
  int wave = threadIdx.x >> 6, lane = threadIdx.x & 63;
  int node = blockIdx.x * 4 + wave;
  int c0 = lane * 4;
  float4 a = gather_node(hn8, rowptr, csr, node, c0);
  float di = dinv[node];
  float4 b = *(const float4*)(bias + c0);
  float r0 = fmaxf(fmaf(di, a.x, b.x), 0.f);
  float r1 = fmaxf(fmaf(di, a.y, b.y), 0.f);
  float r2 = fmaxf(fmaf(di, a.z, b.z), 0.f);
  float r3 = fmaxf(fmaf(di, a.w, b.w), 0.f);
  int p = __builtin_amdgcn_cvt_pk_fp8_f32(r0, r1, 0, false);
  p     = __builtin_amdgcn_cvt_pk_fp8_f32(r2, r3, p, true);
  *(unsigned*)(h1p8 + (size_t)node * 256 + c0) = (unsigned)p;
}

__global__ __launch_bounds__(256) void agg2_kernel(const unsigned char* __restrict__ hn8,
                                                   const float* __restrict__ dinv,
                                                   const int* __restrict__ rowptr,
                                                   const int* __restrict__ csr,
                                                   const float* __restrict__ bias,
                                                   float* __restrict__ partials) {
  __shared__ float sm[1024];
  int wave = threadIdx.x >> 6, lane = threadIdx.x & 63;
  int node = blockIdx.x * 4 + wave;                 // 12500*4 = 50000 exact
  int c0 = lane * 4;
  float4 a = gather_node(hn8, rowptr, csr, node, c0);
  float di = dinv[node];
  float4 b = *(const float4*)(bias + c0);
  sm[wave * 256 + c0 + 0] = fmaxf(fmaf(di, a.x, b.x), 0.f);
  sm[wave * 256 + c0 + 1] = fmaxf(fmaf(di, a.y, b.y), 0.f);
  sm[wave * 256 + c0 + 2] = fmaxf(fmaf(di, a.z, b.z), 0.f);
  sm[wave * 256 + c0 + 3] = fmaxf(fmaf(di, a.w, b.w), 0.f);
  __syncthreads();
  int t = threadIdx.x;
  partials[(size_t)blockIdx.x * 256 + t] = sm[t] + sm[256 + t] + sm[512 + t] + sm[768 + t];
}

// ---------------- readout ----------------
__global__ __launch_bounds__(256) void reduce2_kernel(const float* __restrict__ partials,
                                                      float* __restrict__ p2) {
  int t = threadIdx.x, b = blockIdx.x;              // 64 blocks
  float s = 0.f;
  for (int r = b; r < AGG_BLOCKS; r += RED_BLOCKS) s += partials[(size_t)r * 256 + t];
  p2[b * 256 + t] = s;
}
__global__ __launch_bounds__(256) void final_kernel(const float* __restrict__ p2,
                                                    const float* __restrict__ Wfc,
                                                    const float* __restrict__ bfc,
                                                    float* __restrict__ out) {
  __shared__ float red[256];
  int t = threadIdx.x;
  float s = 0.f;
  for (int b = 0; b < RED_BLOCKS; ++b) s += p2[b * 256 + t];
  float g = s * (1.0f / (float)NODES);
  red[t] = g * Wfc[t];
  __syncthreads();
  for (int off = 128; off > 0; off >>= 1) {
    if (t < off) red[t] += red[t + off];
    __syncthreads();
  }
  if (t == 0) {
    float z = red[0] + bfc[0];
    out[0] = 1.0f / (1.0f + expf(-z));
  }
}

// ---------------- launch ----------------
extern "C" void kernel_launch(void* const* d_in, const int* in_sizes, int n_in,
                              void* d_out, int out_size, void* d_ws, size_t ws_size,
                              hipStream_t stream) {
  (void)in_sizes; (void)n_in; (void)out_size; (void)ws_size;
  const float* x   = (const float*)d_in[0];
  const int*   ei  = (const int*)d_in[1];
  const float* W1  = (const float*)d_in[2];
  const float* b1  = (const float*)d_in[3];
  const float* W2  = (const float*)d_in[4];
  const float* b2  = (const float*)d_in[5];
  const float* Wfc = (const float*)d_in[6];
  const float* bfc = (const float*)d_in[7];
  float* out = (float*)d_out;
  char* ws = (char*)d_ws;

  unsigned char*  hn8  = (unsigned char*)(ws + OFF_HN);
  unsigned char*  h1p8 = (unsigned char*)(ws + OFF_H1P);
  unsigned short* w1t  = (unsigned short*)(ws + OFF_W1T);
  unsigned char*  w2t8 = (unsigned char*)(ws + OFF_W2T8);
  int*   deg    = (int*)(ws + OFF_DEG);
  int*   fill   = (int*)(ws + OFF_FILL);
  int*   rowptr = (int*)(ws + OFF_ROWP);
  int*   csr    = (int*)(ws + OFF_CSR);
  int*   bsum   = (int*)(ws + OFF_BSUM);
  int*   boff   = (int*)(ws + OFF_BOFF);
  float* part   = (float*)(ws + OFF_PART);
  float* p2     = (float*)(ws + OFF_P2);
  float* dinv   = (float*)(ws + OFF_DINV);

  transw_zero_kernel<<<866, 256, 0, stream>>>(W1, W2, w1t, w2t8, (int4*)deg);
  hist_kernel<<<EDGES / 256, 256, 0, stream>>>(ei, deg);
  scan1_kernel<<<NB_SCAN, 256, 0, stream>>>(deg, rowptr, bsum, dinv);
  scan2_kernel<<<1, 256, 0, stream>>>(bsum, boff, rowptr + NODES);
  scan3_kernel<<<NB_SCAN, 256, 0, stream>>>(rowptr, boff);
  fill_kernel<<<EDGES / 256, 256, 0, stream>>>(ei, rowptr, fill, csr);

  gemm1_kernel<<<GEMM_MB256, 512, 0, stream>>>(x, w1t, dinv, hn8);
  agg1_kernel<<<AGG_BLOCKS, 256, 0, stream>>>(hn8, dinv, rowptr, csr, b1, h1p8);
  gemm2_fp8_kernel<<<GEMM_MB256, 512, 0, stream>>>(h1p8, w2t8, dinv, hn8);
  agg2_kernel<<<AGG_BLOCKS, 256, 0, stream>>>(hn8, dinv, rowptr, csr, b2, part);
  reduce2_kernel<<<RED_BLOCKS, 256, 0, stream>>>(part, p2);
  final_kernel<<<1, 256, 0, stream>>>(p2, Wfc, bfc, out);
}

// Round 20
// 223.703 us; speedup vs baseline: 1.9649x; 1.1557x over previous
//
#include <hip/hip_runtime.h>
#include <stdint.h>

#define AS1 __attribute__((address_space(1)))
#define AS3 __attribute__((address_space(3)))

typedef __bf16 bf16x8 __attribute__((ext_vector_type(8)));
typedef float  f32x4  __attribute__((ext_vector_type(4)));

static constexpr int NODES  = 50000;
static constexpr int EDGES  = 800000;
static constexpr int INDIM  = 512;
static constexpr int HIDDIM = 256;
static constexpr int NB_SCAN = (NODES + 255) / 256;   // 196
static constexpr int AGG_BLOCKS = NODES / 4;          // 12500 (agg1)
static constexpr int AGG2_BLOCKS = 2048;              // grid-stride agg2
static constexpr int RED_BLOCKS = 64;
static constexpr int GEMM_MB256 = (NODES + 255) / 256; // 196 row-blocks (BM=256)

// ---------------- ws layout (bytes) ----------------
static constexpr size_t OFF_PART = 0;            // f32  [2048][256] (2 MB)
static constexpr size_t OFF_HN   = 51200000;     // fp8  [50000][256] pre-scaled h (both layers)
static constexpr size_t OFF_H1P  = 76800000;     // fp8  [50000][256] relu(layer1) output
static constexpr size_t OFF_W1T  = 102400000;    // bf16 [256][512]
static constexpr size_t OFF_W2T8 = 102662144;    // fp8  [256][256]
static constexpr size_t OFF_DEG  = 102793216;    // i32 [50000]
static constexpr size_t OFF_FILL = 102993216;    // i32 [50000]
static constexpr size_t OFF_ROWP = 103193216;    // i32 [50001]
static constexpr size_t OFF_CSR  = 103393280;    // i32 [800000]
static constexpr size_t OFF_BSUM = 106593280;    // i32 [196]
static constexpr size_t OFF_BOFF = 106594304;    // i32 [256]
static constexpr size_t OFF_P2   = 106595840;    // f32 [64][256]
static constexpr size_t OFF_DINV = 106661376;    // f32 [50000]

__device__ __forceinline__ unsigned short f2bf(float f) {
  unsigned u = __builtin_bit_cast(unsigned, f);
  unsigned r = (u + 0x7FFFu + ((u >> 16) & 1u)) >> 16;   // RNE
  return (unsigned short)r;
}
__device__ __forceinline__ unsigned char f2fp8(float f) {
  int p = __builtin_amdgcn_cvt_pk_fp8_f32(f, f, 0, false);   // OCP e4m3fn
  return (unsigned char)(p & 0xff);
}
__device__ __forceinline__ void acc_fp8(float4& a, unsigned u) {
  a.x += __builtin_amdgcn_cvt_f32_fp8(u, 0);
  a.y += __builtin_amdgcn_cvt_f32_fp8(u, 1);
  a.z += __builtin_amdgcn_cvt_f32_fp8(u, 2);
  a.w += __builtin_amdgcn_cvt_f32_fp8(u, 3);
}
__device__ __forceinline__ void gload_lds16(const void* g, void* l) {
  __builtin_amdgcn_global_load_lds((const AS1 void*)g, (AS3 void*)l, 16, 0, 0);
}

// counted-wait primitives (T4)
#define WAITVM(N)  asm volatile("s_waitcnt vmcnt(" #N ")" ::: "memory")
#define WAITLGKM   asm volatile("s_waitcnt lgkmcnt(0)" ::: "memory")
#define HWBARRIER  { asm volatile("" ::: "memory"); __builtin_amdgcn_s_barrier(); \
                     asm volatile("" ::: "memory"); }

// ---- LDS-bounce epilogue (R19, confirmed -10.5us): byte-writes to swizzled
// LDS, barrier, coalesced dwordx4 global stores ----
#define BOUNCE_EPILOGUE                                                       \
  {                                                                           \
    char* Lb = SMEM;                                                          \
    const int rq = q * 4;                                                     \
    _Pragma("unroll")                                                         \
    for (int m = 0; m < 8; ++m) {                                             \
      _Pragma("unroll")                                                       \
      for (int r = 0; r < 4; ++r) {                                           \
        int rt = wr * 128 + m * 16 + rq + r;                                  \
        int grow = m0 + rt;                                                   \
        if (grow < NODES) {                                                   \
          float dv = dinv[grow];                                              \
          _Pragma("unroll")                                                   \
          for (int n = 0; n < 4; ++n) {                                       \
            int ch = (wc * 4 + n) ^ (rt & 15);                                \
            Lb[rt * 256 + ch * 16 + fr] = (char)f2fp8(acc[m][n][r] * dv);     \
          }                                                                   \
        }                                                                     \
      }                                                                       \
    }                                                                         \
    HWBARRIER;                                                                \
    _Pragma("unroll")                                                         \
    for (int p = 0; p < 8; ++p) {                                             \
      int idx = p * 512 + tid;              /* 0..4095: (row, 16B seg) */     \
      int rt = idx >> 4, seg = idx & 15;                                      \
      int grow = m0 + rt;                                                     \
      if (grow < NODES)                                                       \
        *(uint4*)(Cn8 + (size_t)grow * 256 + seg * 16) =                      \
            *(const uint4*)(Lb + rt * 256 + ((seg ^ (rt & 15)) * 16));        \
    }                                                                         \
  }

// -------- weight prep: W1T bf16, W2T fp8 + scratch zeroing (fused) --------
__global__ __launch_bounds__(256) void transw_zero_kernel(const float* __restrict__ W1,
                                                          const float* __restrict__ W2,
                                                          unsigned short* __restrict__ W1T,
                                                          unsigned char* __restrict__ W2T8,
                                                          int4* __restrict__ zreg) {
  int b = blockIdx.x, tid = threadIdx.x;
  if (b < 512) {                                    // W1T[n][k] = bf16(W1[k][n])
    int t = b * 256 + tid; int n = t >> 9, k = t & 511;
    W1T[t] = f2bf(W1[k * HIDDIM + n]);
  } else if (b < 768) {                             // W2T8[n][k] = fp8(W2[k][n])
    int u = (b - 512) * 256 + tid; int n = u >> 8, k = u & 255;
    W2T8[u] = f2fp8(W2[k * HIDDIM + n]);
  } else {                                          // zero deg+fill (400000 B)
    int i = (b - 768) * 256 + tid;
    if (i < 25000) zreg[i] = int4{0, 0, 0, 0};
  }
}

// ---------------- degree histogram (inline int64-layout detect) ----------------
__global__ __launch_bounds__(256) void hist_kernel(const int* __restrict__ ei,
                                                   int* __restrict__ deg) {
  __shared__ int sflag;
  if (threadIdx.x < 64) {
    unsigned long long b = __ballot(ei[2 * threadIdx.x + 1] == 0);
    if (threadIdx.x == 0) sflag = (b == 0xFFFFFFFFFFFFFFFFull) ? 1 : 0;
  }
  __syncthreads();
  int f = sflag;
  int e = blockIdx.x * 256 + threadIdx.x;        // 3125*256 = 800000 exact
  int d = f ? ei[2 * (EDGES + e)] : ei[EDGES + e];
  atomicAdd(&deg[d], 1);
}

// ---------------- scan (3 kernels) + dinv ----------------
__global__ __launch_bounds__(256) void scan1_kernel(const int* __restrict__ deg,
                                                    int* __restrict__ rowptr,
                                                    int* __restrict__ bsum,
                                                    float* __restrict__ dinv) {
  __shared__ int s[256];
  int t = threadIdx.x, i = blockIdx.x * 256 + t;
  int v = (i < NODES) ? deg[i] : 0;
  if (i < NODES) dinv[i] = rsqrtf((float)(v + 1));   // +1 self-loop
  s[t] = v; __syncthreads();
  for (int off = 1; off < 256; off <<= 1) {
    int x = (t >= off) ? s[t - off] : 0;
    __syncthreads(); s[t] += x; __syncthreads();
  }
  if (i < NODES) rowptr[i] = s[t] - v;
  if (t == 255) bsum[blockIdx.x] = s[255];
}
__global__ __launch_bounds__(256) void scan2_kernel(const int* __restrict__ bsum,
                                                    int* __restrict__ boff,
                                                    int* __restrict__ rowptrN) {
  __shared__ int s[256];
  int t = threadIdx.x;
  int v = (t < NB_SCAN) ? bsum[t] : 0;
  s[t] = v; __syncthreads();
  for (int off = 1; off < 256; off <<= 1) {
    int x = (t >= off) ? s[t - off] : 0;
    __syncthreads(); s[t] += x; __syncthreads();
  }
  if (t < NB_SCAN) boff[t] = s[t] - v;
  if (t == 255) *rowptrN = s[255];
}
__global__ __launch_bounds__(256) void scan3_kernel(int* __restrict__ rowptr,
                                                    const int* __restrict__ boff) {
  int i = blockIdx.x * 256 + threadIdx.x;
  if (i < NODES) rowptr[i] += boff[blockIdx.x];
}

// ---------------- CSR fill (inline detect) ----------------
__global__ __launch_bounds__(256) void fill_kernel(const int* __restrict__ ei,
                                                   const int* __restrict__ rowptr,
                                                   int* __restrict__ fill,
                                                   int* __restrict__ csr) {
  __shared__ int sflag;
  if (threadIdx.x < 64) {
    unsigned long long b = __ballot(ei[2 * threadIdx.x + 1] == 0);
    if (threadIdx.x == 0) sflag = (b == 0xFFFFFFFFFFFFFFFFull) ? 1 : 0;
  }
  __syncthreads();
  int f = sflag;
  int e = blockIdx.x * 256 + threadIdx.x;
  int s, d;
  if (f) { s = ei[2 * e]; d = ei[2 * (EDGES + e)]; }
  else   { s = ei[e];     d = ei[EDGES + e]; }
  int p = atomicAdd(&fill[d], 1);
  csr[rowptr[d] + p] = s;
}

// ------- GEMM1: BM=BN=256, BK=32, counted vmcnt, bf16 MFMA, bounce epilogue -------
__global__ __launch_bounds__(512, 2) void gemm1_kernel(const float* __restrict__ A,
                                                       const unsigned short* __restrict__ BT,
                                                       const float* __restrict__ dinv,
                                                       unsigned char* __restrict__ Cn8) {
  constexpr int K = INDIM, NSTEP = K / 32;
  __shared__ char SMEM[65536];
  unsigned short (*As)[8192] = (unsigned short (*)[8192])SMEM;          // 2x16KB
  unsigned short (*Bs)[8192] = (unsigned short (*)[8192])(SMEM + 32768);// 2x16KB
  const int tid = threadIdx.x, wave = tid >> 6, lane = tid & 63;
  const int fr = lane & 15, q = lane >> 4;
  const int wr = wave >> 2, wc = wave & 3;     // 2m x 4n
  const int m0 = blockIdx.x * 256;

  const int lrow4 = lane >> 2;                 // 0..15: row within 16-row slab
  const int sgq   = (lane & 3) ^ (lrow4 & 3);  // pre-swizzled source 16B group

  f32x4 acc[8][4] = {};
  float4 fa[4];                                // fp32 A staging regs

#define STAGE_B(buf, kb)                                                      \
  {                                                                           \
    _Pragma("unroll")                                                         \
    for (int c = 0; c < 2; ++c) {                                             \
      int rbase = wave * 32 + c * 16;                                         \
      int gr = rbase + lrow4;                                                 \
      gload_lds16(BT + (size_t)gr * K + (kb) + sgq * 8, &Bs[buf][rbase * 32]);\
    }                                                                         \
  }
#define LOAD_A32(kb)                                                          \
  {                                                                           \
    _Pragma("unroll")                                                         \
    for (int j = 0; j < 4; ++j) {                                             \
      int F = tid + j * 512;                                                  \
      int r0 = m0 + (F >> 3); if (r0 > NODES - 1) r0 = NODES - 1;             \
      fa[j] = *(const float4*)(A + (size_t)r0 * K + (kb) + (F & 7) * 4);      \
    }                                                                         \
  }
#define WRITE_A32(buf)                                                        \
  {                                                                           \
    _Pragma("unroll")                                                         \
    for (int j = 0; j < 4; ++j) {                                             \
      int F = tid + j * 512;                                                  \
      int row = F >> 3, g4 = F & 7;                                           \
      ushort4 o{f2bf(fa[j].x), f2bf(fa[j].y), f2bf(fa[j].z), f2bf(fa[j].w)};  \
      int col = (((g4 >> 1) ^ (row & 3)) * 8) + (g4 & 1) * 4;                 \
      *(ushort4*)&As[buf][row * 32 + col] = o;                                \
    }                                                                         \
  }

  LOAD_A32(0); WRITE_A32(0); WAITLGKM;
  STAGE_B(0, 0);

  for (int t = 0; t < NSTEP; ++t) {
    const int cur = t & 1, nxt = cur ^ 1;
    if (t + 1 < NSTEP) {
      const int kb1 = (t + 1) * 32;
      LOAD_A32(kb1);
      STAGE_B(nxt, kb1);
      WAITVM(6);
    } else {
      WAITVM(0);
    }
    HWBARRIER;

    bf16x8 af[8], bq[4];
#pragma unroll
    for (int m = 0; m < 8; ++m) {
      int row = wr * 128 + m * 16 + fr;
      af[m] = *(const bf16x8*)&As[cur][row * 32 + ((q ^ (row & 3)) * 8)];
    }
#pragma unroll
    for (int n = 0; n < 4; ++n) {
      int row = wc * 64 + n * 16 + fr;
      bq[n] = *(const bf16x8*)&Bs[cur][row * 32 + ((q ^ (row & 3)) * 8)];
    }
#pragma unroll
    for (int m = 0; m < 8; ++m)
#pragma unroll
      for (int n = 0; n < 4; ++n)
        acc[m][n] = __builtin_amdgcn_mfma_f32_16x16x32_bf16(af[m], bq[n], acc[m][n], 0, 0, 0);

    if (t + 1 < NSTEP) { WRITE_A32(nxt); WAITLGKM; }
    HWBARRIER;
  }
#undef STAGE_B
#undef LOAD_A32
#undef WRITE_A32

  BOUNCE_EPILOGUE;
}

// ------- GEMM2: fp8 memory + native fp8 MFMA, BK=64, bounce epilogue -------
__global__ __launch_bounds__(512, 2) void gemm2_fp8_kernel(const unsigned char* __restrict__ A8,
                                                           const unsigned char* __restrict__ BT8,
                                                           const float* __restrict__ dinv,
                                                           unsigned char* __restrict__ Cn8) {
  constexpr int K = HIDDIM, NSTEP = K / 64;    // 4
  __shared__ char SMEM[65536];
  unsigned char (*As)[16384] = (unsigned char (*)[16384])SMEM;           // 2x16KB
  unsigned char (*Bs)[16384] = (unsigned char (*)[16384])(SMEM + 32768); // 2x16KB
  const int tid = threadIdx.x, wave = tid >> 6, lane = tid & 63;
  const int fr = lane & 15, q = lane >> 4;
  const int wr = wave >> 2, wc = wave & 3;     // 2m x 4n
  const int m0 = blockIdx.x * 256;

  const int srl0 = lane >> 2, sch = lane & 3;  // staging: (row lane>>2, 16B grp lane&3)

  f32x4 acc[8][4] = {};

#define STAGE_T(dstArr, buf, srcp, rowbase, kb, CLAMP)                        \
  {                                                                           \
    _Pragma("unroll")                                                         \
    for (int c = 0; c < 2; ++c) {                                             \
      int rl = (wave * 2 + c) * 16 + srl0;                                    \
      int gr = (rowbase) + rl;                                                \
      if (CLAMP) { if (gr > NODES - 1) gr = NODES - 1; }                      \
      const unsigned char* sp = srcp + (size_t)gr * K + (kb) +                \
                                ((sch ^ (rl & 3)) << 4);                      \
      gload_lds16(sp, &dstArr[buf][(wave * 2 + c) * 1024]);                   \
    }                                                                         \
  }

  STAGE_T(As, 0, A8, m0, 0, true);
  STAGE_T(Bs, 0, BT8, 0, 0, false);

  for (int t = 0; t < NSTEP; ++t) {
    const int cur = t & 1, nxt = cur ^ 1;
    if (t + 1 < NSTEP) {
      const int kb1 = (t + 1) * 64;
      STAGE_T(As, nxt, A8, m0, kb1, true);
      STAGE_T(Bs, nxt, BT8, 0, kb1, false);
      WAITVM(4);
    } else {
      WAITVM(0);
    }
    HWBARRIER;

#pragma unroll
    for (int s = 0; s < 2; ++s) {               // two K=32 slabs per step
      long af[8], bq[4];
#pragma unroll
      for (int m = 0; m < 8; ++m) {
        int row = wr * 128 + m * 16 + fr;
        int cch = s * 2 + (q >> 1);
        af[m] = *(const long*)
            &As[cur][row * 64 + ((cch ^ (row & 3)) << 4) + (q & 1) * 8];
      }
#pragma unroll
      for (int n = 0; n < 4; ++n) {
        int row = wc * 64 + n * 16 + fr;
        int cch = s * 2 + (q >> 1);
        bq[n] = *(const long*)
            &Bs[cur][row * 64 + ((cch ^ (row & 3)) << 4) + (q & 1) * 8];
      }
#pragma unroll
      for (int m = 0; m < 8; ++m)
#pragma unroll
        for (int n = 0; n < 4; ++n)
          acc[m][n] = __builtin_amdgcn_mfma_f32_16x16x32_fp8_fp8(af[m], bq[n], acc[m][n], 0, 0, 0);
    }
    HWBARRIER;
  }
#undef STAGE_T

  BOUNCE_EPILOGUE;
}

// --- gather core: SGPR-uniform csr indices, unroll-16/8/4/scalar (R18) ---
__device__ __forceinline__ float4 gather_node(const unsigned char* __restrict__ hn8,
                                              const int* __restrict__ rowptr,
                                              const int* __restrict__ csr,
                                              int node, int boff) {
  float4 A{0.f, 0.f, 0.f, 0.f}, B{0.f, 0.f, 0.f, 0.f};
  acc_fp8(A, *(const unsigned*)(hn8 + (size_t)node * 256 + boff));   // self-loop
  int e0  = __builtin_amdgcn_readfirstlane(rowptr[node]);
  int cnt = __builtin_amdgcn_readfirstlane(rowptr[node + 1]) - e0;
  const int* cp = csr + e0;
  int i = 0;
  for (; i + 16 <= cnt; i += 16) {
    unsigned v[16];
#pragma unroll
    for (int j = 0; j < 16; ++j)
      v[j] = *(const unsigned*)(hn8 + (size_t)cp[i + j] * 256 + boff);
#pragma unroll
    for (int j = 0; j < 16; j += 2) { acc_fp8(A, v[j]); acc_fp8(B, v[j + 1]); }
  }
  for (; i + 8 <= cnt; i += 8) {
    unsigned v[8];
#pragma unroll
    for (int j = 0; j < 8; ++j)
      v[j] = *(const unsigned*)(hn8 + (size_t)cp[i + j] * 256 + boff);
#pragma unroll
    for (int j = 0; j < 8; j += 2) { acc_fp8(A, v[j]); acc_fp8(B, v[j + 1]); }
  }
  for (; i + 4 <= cnt; i += 4) {
    unsigned v[4];
#pragma unroll
    for (int j = 0; j < 4; ++j)
      v[j] = *(const unsigned*)(hn8 + (size_t)cp[i + j] * 256 + boff);
    acc_fp8(A, v[0]); acc_fp8(B, v[1]); acc_fp8(A, v[2]); acc_fp8(B, v[3]);
  }
  for (; i < cnt; ++i)
    acc_fp8(A, *(const unsigned*)(hn8 + (size_t)cp[i] * 256 + boff));
  return float4{A.x + B.x, A.y + B.y, A.z + B.z, A.w + B.w};
}

// ---------------- agg1: per-node fp8 output (12500 blocks) ----------------
__global__ __launch_bounds__(256) void agg1_kernel(const unsigned char* __restrict__ hn8,
                                                   const float* __restrict__ dinv,
                                                   const int* __restrict__ rowptr,
                                                   const int* __restrict__ csr,
                                                   const float* __restrict__ bias,
                                                   unsigned char* __restrict__ h1p8) {
  int wave = threadIdx.x >> 6, lane = threadIdx.x & 63;
  int node = blockIdx.x * 4 + wave;
  int c0 = lane * 4;
  float4 a = gather_node(hn8, rowptr, csr, node, c0);
  float di = dinv[node];
  float4 b = *(const float4*)(bias + c0);
  float r0 = fmaxf(fmaf(di, a.x, b.x), 0.f);
  float r1 = fmaxf(fmaf(di, a.y, b.y), 0.f);
  float r2 = fmaxf(fmaf(di, a.z, b.z), 0.f);
  float r3 = fmaxf(fmaf(di, a.w, b.w), 0.f);
  int p = __builtin_amdgcn_cvt_pk_fp8_f32(r0, r1, 0, false);
  p     = __builtin_amdgcn_cvt_pk_fp8_f32(r2, r3, p, true);
  *(unsigned*)(h1p8 + (size_t)node * 256 + c0) = (unsigned)p;
}

// ------- agg2: grid-stride (2048 blocks), register accumulation across nodes;
//         one 1KB partials write per block (partials 12.8MB -> 2MB) -------
__global__ __launch_bounds__(256) void agg2_kernel(const unsigned char* __restrict__ hn8,
                                                   const float* __restrict__ dinv,
                                                   const int* __restrict__ rowptr,
                                                   const int* __restrict__ csr,
                                                   const float* __restrict__ bias,
                                                   float* __restrict__ partials) {
  __shared__ float sm[1024];
  int wave = threadIdx.x >> 6, lane = threadIdx.x & 63;
  int c0 = lane * 4;
  float4 bq = *(const float4*)(bias + c0);
  float s0 = 0.f, s1 = 0.f, s2 = 0.f, s3 = 0.f;
  for (int node = blockIdx.x * 4 + wave; node < NODES; node += AGG2_BLOCKS * 4) {
    float4 a = gather_node(hn8, rowptr, csr, node, c0);
    float di = dinv[node];
    s0 += fmaxf(fmaf(di, a.x, bq.x), 0.f);
    s1 += fmaxf(fmaf(di, a.y, bq.y), 0.f);
    s2 += fmaxf(fmaf(di, a.z, bq.z), 0.f);
    s3 += fmaxf(fmaf(di, a.w, bq.w), 0.f);
  }
  sm[wave * 256 + c0 + 0] = s0;
  sm[wave * 256 + c0 + 1] = s1;
  sm[wave * 256 + c0 + 2] = s2;
  sm[wave * 256 + c0 + 3] = s3;
  __syncthreads();
  int t = threadIdx.x;
  partials[(size_t)blockIdx.x * 256 + t] = sm[t] + sm[256 + t] + sm[512 + t] + sm[768 + t];
}

// ---------------- readout ----------------
__global__ __launch_bounds__(256) void reduce2_kernel(const float* __restrict__ partials,
                                                      float* __restrict__ p2) {
  int t = threadIdx.x, b = blockIdx.x;              // 64 blocks
  float s = 0.f;
  for (int r = b; r < AGG2_BLOCKS; r += RED_BLOCKS) s += partials[(size_t)r * 256 + t];
  p2[b * 256 + t] = s;
}
__global__ __launch_bounds__(256) void final_kernel(const float* __restrict__ p2,
                                                    const float* __restrict__ Wfc,
                                                    const float* __restrict__ bfc,
                                                    float* __restrict__ out) {
  __shared__ float red[256];
  int t = threadIdx.x;
  float s = 0.f;
  for (int b = 0; b < RED_BLOCKS; ++b) s += p2[b * 256 + t];
  float g = s * (1.0f / (float)NODES);
  red[t] = g * Wfc[t];
  __syncthreads();
  for (int off = 128; off > 0; off >>= 1) {
    if (t < off) red[t] += red[t + off];
    __syncthreads();
  }
  if (t == 0) {
    float z = red[0] + bfc[0];
    out[0] = 1.0f / (1.0f + expf(-z));
  }
}

// ---------------- launch ----------------
extern "C" void kernel_launch(void* const* d_in, const int* in_sizes, int n_in,
                              void* d_out, int out_size, void* d_ws, size_t ws_size,
                              hipStream_t stream) {
  (void)in_sizes; (void)n_in; (void)out_size; (void)ws_size;
  const float* x   = (const float*)d_in[0];
  const int*   ei  = (const int*)d_in[1];
  const float* W1  = (const float*)d_in[2];
  const float* b1  = (const float*)d_in[3];
  const float* W2  = (const float*)d_in[4];
  const float* b2  = (const float*)d_in[5];
  const float* Wfc = (const float*)d_in[6];
  const float* bfc = (const float*)d_in[7];
  float* out = (float*)d_out;
  char* ws = (char*)d_ws;

  unsigned char*  hn8  = (unsigned char*)(ws + OFF_HN);
  unsigned char*  h1p8 = (unsigned char*)(ws + OFF_H1P);
  unsigned short* w1t  = (unsigned short*)(ws + OFF_W1T);
  unsigned char*  w2t8 = (unsigned char*)(ws + OFF_W2T8);
  int*   deg    = (int*)(ws + OFF_DEG);
  int*   fill   = (int*)(ws + OFF_FILL);
  int*   rowptr = (int*)(ws + OFF_ROWP);
  int*   csr    = (int*)(ws + OFF_CSR);
  int*   bsum   = (int*)(ws + OFF_BSUM);
  int*   boff   = (int*)(ws + OFF_BOFF);
  float* part   = (float*)(ws + OFF_PART);
  float* p2     = (float*)(ws + OFF_P2);
  float* dinv   = (float*)(ws + OFF_DINV);

  transw_zero_kernel<<<866, 256, 0, stream>>>(W1, W2, w1t, w2t8, (int4*)deg);
  hist_kernel<<<EDGES / 256, 256, 0, stream>>>(ei, deg);
  scan1_kernel<<<NB_SCAN, 256, 0, stream>>>(deg, rowptr, bsum, dinv);
  scan2_kernel<<<1, 256, 0, stream>>>(bsum, boff, rowptr + NODES);
  scan3_kernel<<<NB_SCAN, 256, 0, stream>>>(rowptr, boff);
  fill_kernel<<<EDGES / 256, 256, 0, stream>>>(ei, rowptr, fill, csr);

  gemm1_kernel<<<GEMM_MB256, 512, 0, stream>>>(x, w1t, dinv, hn8);
  agg1_kernel<<<AGG_BLOCKS, 256, 0, stream>>>(hn8, dinv, rowptr, csr, b1, h1p8);
  gemm2_fp8_kernel<<<GEMM_MB256, 512, 0, stream>>>(h1p8, w2t8, dinv, hn8);
  agg2_kernel<<<AGG2_BLOCKS, 256, 0, stream>>>(hn8, dinv, rowptr, csr, b2, part);
  reduce2_kernel<<<RED_BLOCKS, 256, 0, stream>>>(part, p2);
  final_kernel<<<1, 256, 0, stream>>>(p2, Wfc, bfc, out);
}